// Round 1
// baseline (863.465 us; speedup 1.0000x reference)
//
#include <hip/hip_runtime.h>

typedef unsigned short ushort;
using short8 = __attribute__((ext_vector_type(8))) short;
using f32x4  = __attribute__((ext_vector_type(4))) float;
using i32x4  = __attribute__((ext_vector_type(4))) int;

static __device__ __forceinline__ float bf2f(ushort u) {
  union { unsigned int i; float f; } x; x.i = ((unsigned int)u) << 16; return x.f;
}
static __device__ __forceinline__ ushort f2bf(float f) {
  union { float f; unsigned int i; } x; x.f = f;
  unsigned int u = x.i;
  unsigned int r = u + 0x7fffu + ((u >> 16) & 1u);
  return (ushort)(r >> 16);
}

// ---------------- weight prep ----------------
// out[c][r] = bf16(in[r][c]) for c < C, 0 for C <= c < Cout (grid.x*32). R % 32 == 0.
__global__ __launch_bounds__(256) void wtrans_kernel(const float* __restrict__ in,
                                                     ushort* __restrict__ out,
                                                     int R, int C) {
  __shared__ float sl[32][33];
  int tx = threadIdx.x & 31, ty = threadIdx.x >> 5;  // ty 0..7
  int c0 = blockIdx.x * 32, r0 = blockIdx.y * 32;
#pragma unroll
  for (int s = 0; s < 4; s++) {
    int r = r0 + ty + s * 8;
    int c = c0 + tx;
    sl[ty + s * 8][tx] = (c < C) ? in[(size_t)r * C + c] : 0.f;
  }
  __syncthreads();
#pragma unroll
  for (int s = 0; s < 4; s++) {
    int c = c0 + ty + s * 8;
    int r = r0 + tx;
    out[(size_t)c * R + r] = f2bf(sl[tx][ty + s * 8]);
  }
}

__global__ void wsplit_kernel(const float* __restrict__ in, ushort* __restrict__ hi,
                              ushort* __restrict__ lo, int n) {
  int i = blockIdx.x * 256 + threadIdx.x;
  if (i < n) {
    float v = in[i];
    ushort h = f2bf(v);
    hi[i] = h;
    lo[i] = f2bf(v - bf2f(h));
  }
}

// ---------------- LayerNorm (over dim=960 for each (nm,t)) ----------------
// K1a: partial sums over cv chunks; x layout [nm][cv][t], reads fully coalesced.
__global__ __launch_bounds__(256) void ln_part_kernel(const float* __restrict__ x,
                                                      float* __restrict__ part) {
  int nm = blockIdx.y, ch = blockIdx.x, t = threadIdx.x;
  float s = 0.f, ss = 0.f;
  const float* base = x + ((size_t)nm * 960 + (size_t)ch * 240) * 256 + t;
#pragma unroll 4
  for (int r = 0; r < 240; r++) {
    float v = base[(size_t)r * 256];
    s += v; ss += v * v;
  }
  float2 o; o.x = s; o.y = ss;
  ((float2*)part)[(nm * 4 + ch) * 256 + t] = o;
}

__global__ __launch_bounds__(256) void ln_stat_kernel(const float* __restrict__ part,
                                                      float* __restrict__ stat) {
  int nm = blockIdx.x, t = threadIdx.x;
  float s = 0.f, ss = 0.f;
#pragma unroll
  for (int ch = 0; ch < 4; ch++) {
    float2 p = ((const float2*)part)[(nm * 4 + ch) * 256 + t];
    s += p.x; ss += p.y;
  }
  float mean = s * (1.f / 960.f);
  float var = ss * (1.f / 960.f) - mean * mean;
  float2 o; o.x = mean; o.y = rsqrtf(var + 1e-5f);
  ((float2*)stat)[nm * 256 + t] = o;
}

// K1c: tiled transpose + normalize -> xn bf16 [nm*256+t][960]
__global__ __launch_bounds__(256) void ln_apply_kernel(const float* __restrict__ x,
                                                       const float* __restrict__ stat,
                                                       const float* __restrict__ g,
                                                       const float* __restrict__ b,
                                                       ushort* __restrict__ xn) {
  __shared__ float sl[64][65];
  int nm = blockIdx.y;
  int tb = blockIdx.x & 3, cvb = blockIdx.x >> 2;
  int t0 = tb * 64, cv0 = cvb * 64;
  int tx = threadIdx.x & 63, ty = threadIdx.x >> 6;
#pragma unroll
  for (int s = 0; s < 16; s++) {
    int r = ty + s * 4;  // cv_local
    sl[r][tx] = x[((size_t)nm * 960 + cv0 + r) * 256 + t0 + tx];
  }
  __syncthreads();
  float gg = g[cv0 + tx], bb = b[cv0 + tx];
#pragma unroll
  for (int s = 0; s < 16; s++) {
    int tt = ty + s * 4;  // t_local
    float2 ms = ((const float2*)stat)[nm * 256 + t0 + tt];
    float v = (sl[tx][tt] - ms.x) * ms.y * gg + bb;
    xn[((size_t)nm * 256 + t0 + tt) * 960 + cv0 + tx] = f2bf(v);
  }
}

// ---------------- generic bf16 MFMA GEMM, C = A @ B  (B given transposed: BT[col][k]) ----
// 128x128 tile, BK=32, 4 waves (2x2), each wave 64x64 (4x4 frags of 16x16x32).
// MODE 0: QKV epilogue (scatter q*scale, k, vT)
// MODE 1: out-proj epilogue (bf16 proj + b_out)
// MODE 2: final 3-segment split-bf16 (A,BT / A,Blo / Alo,BT), tanh + b_lin -> f32 out
template <int MODE>
__global__ __launch_bounds__(256) void gemm_bt(
    const ushort* __restrict__ A, int lda, const ushort* __restrict__ BT, int ldb, int nkt,
    const ushort* __restrict__ Alo, const ushort* __restrict__ Blo,
    ushort* __restrict__ o0, ushort* __restrict__ o1, ushort* __restrict__ o2,
    const float* __restrict__ bias, float* __restrict__ fout) {
  __shared__ ushort Ash[128 * 40];  // rows padded to 40 elems (80B) -> 2-way max on b128 reads
  __shared__ ushort Bsh[128 * 40];
  int tid = threadIdx.x;
  int l = tid & 63, w = tid >> 6;
  int wr = w >> 1, wc = w & 1;
  int lr = l & 15, lg = l >> 4;
  int cb = blockIdx.x * 128, rb = blockIdx.y * 128;
  f32x4 acc[4][4];
#pragma unroll
  for (int i = 0; i < 4; i++)
#pragma unroll
    for (int j = 0; j < 4; j++) acc[i][j] = (f32x4){0.f, 0.f, 0.f, 0.f};

  for (int kt = 0; kt < nkt; kt++) {
    const ushort* Ap;
    const ushort* Bp;
    int k0;
    if (MODE == 2) {
      int seg = kt >> 3;
      k0 = (kt & 7) * 32;
      Ap = (seg == 2) ? Alo : A;
      Bp = (seg == 1) ? Blo : BT;
    } else {
      Ap = A; Bp = BT; k0 = kt * 32;
    }
    __syncthreads();
#pragma unroll
    for (int u = 0; u < 2; u++) {
      int i = tid + u * 256;
      int row = i >> 2, c = i & 3;
      *(i32x4*)&Ash[row * 40 + c * 8] =
          *(const i32x4*)(Ap + (size_t)(rb + row) * lda + k0 + c * 8);
      *(i32x4*)&Bsh[row * 40 + c * 8] =
          *(const i32x4*)(Bp + (size_t)(cb + row) * ldb + k0 + c * 8);
    }
    __syncthreads();
    short8 a[4], b[4];
#pragma unroll
    for (int i = 0; i < 4; i++)
      a[i] = *(const short8*)&Ash[(wr * 64 + i * 16 + lr) * 40 + lg * 8];
#pragma unroll
    for (int j = 0; j < 4; j++)
      b[j] = *(const short8*)&Bsh[(wc * 64 + j * 16 + lr) * 40 + lg * 8];
#pragma unroll
    for (int i = 0; i < 4; i++)
#pragma unroll
      for (int j = 0; j < 4; j++)
        acc[i][j] = __builtin_amdgcn_mfma_f32_16x16x32_bf16(a[i], b[j], acc[i][j], 0, 0, 0);
  }

  int row0 = rb + wr * 64, col0 = cb + wc * 64;
#pragma unroll
  for (int i = 0; i < 4; i++) {
#pragma unroll
    for (int j = 0; j < 4; j++) {
      f32x4 v = acc[i][j];
#pragma unroll
      for (int r = 0; r < 4; r++) {
        int row = row0 + i * 16 + lg * 4 + r;
        int col = col0 + j * 16 + lr;
        float val = v[r];
        if (MODE == 0) {
          int nm = row >> 8, t = row & 255;
          int which = col >> 10, cl = col & 1023;
          int h = cl >> 7, d = cl & 127;
          int nmh = nm * 8 + h;
          if (which == 0)
            o0[((size_t)nmh * 256 + t) * 128 + d] = f2bf(val * 0.08838834764831845f);
          else if (which == 1)
            o1[((size_t)nmh * 256 + t) * 128 + d] = f2bf(val);
          else
            o2[((size_t)nmh * 128 + d) * 256 + t] = f2bf(val);  // V^T
        } else if (MODE == 1) {
          float bb = (col < 960) ? bias[col] : 0.f;
          o0[(size_t)row * 1024 + col] = f2bf(val + bb);
        } else {
          fout[(size_t)row * 256 + col] = tanhf(val + bias[col]);
        }
      }
    }
  }
}

// ---------------- fused attention: 64 q-rows per block, full T=256 in regs ----------------
__global__ __launch_bounds__(256) void attn_kernel(const ushort* __restrict__ q,
                                                   const ushort* __restrict__ kb,
                                                   const ushort* __restrict__ vT,
                                                   ushort* __restrict__ ao) {
  __shared__ ushort KVs[128 * 72];  // K tile [64][136] or vT tile [128][72] (time-shared)
  __shared__ ushort Ps[64 * 264];   // P tile [64 rows][256 cols], stride 264
  int tid = threadIdx.x;
  int l = tid & 63, w = tid >> 6;
  int lr = l & 15, lg = l >> 4;
  int qb = blockIdx.x;   // 0..3
  int nmh = blockIdx.y;  // 0..1023

  // Q fragments straight from global (q pre-scaled by 1/sqrt(D))
  short8 aq[4];
  {
    const ushort* qp = q + ((size_t)nmh * 256 + qb * 64 + w * 16 + lr) * 128 + lg * 8;
#pragma unroll
    for (int kk = 0; kk < 4; kk++) aq[kk] = *(const short8*)(qp + kk * 32);
  }

  f32x4 s_acc[16];
#pragma unroll
  for (int f = 0; f < 16; f++) s_acc[f] = (f32x4){0.f, 0.f, 0.f, 0.f};

  for (int ct = 0; ct < 4; ct++) {
    __syncthreads();
#pragma unroll
    for (int u = 0; u < 4; u++) {
      int i = tid + u * 256;
      int r = i >> 4, c = i & 15;
      *(i32x4*)&KVs[r * 136 + c * 8] =
          *(const i32x4*)(kb + ((size_t)nmh * 256 + ct * 64 + r) * 128 + c * 8);
    }
    __syncthreads();
#pragma unroll
    for (int j = 0; j < 4; j++) {
      short8 bk[4];
#pragma unroll
      for (int kk = 0; kk < 4; kk++)
        bk[kk] = *(const short8*)&KVs[(j * 16 + lr) * 136 + kk * 32 + lg * 8];
#pragma unroll
      for (int kk = 0; kk < 4; kk++)
        s_acc[ct * 4 + j] =
            __builtin_amdgcn_mfma_f32_16x16x32_bf16(aq[kk], bk[kk], s_acc[ct * 4 + j], 0, 0, 0);
    }
  }

  // softmax over each row (rows live in lanes lg, regs r; cols across lr and 16 frags)
  float m[4] = {-1e30f, -1e30f, -1e30f, -1e30f};
#pragma unroll
  for (int f = 0; f < 16; f++)
#pragma unroll
    for (int r = 0; r < 4; r++) m[r] = fmaxf(m[r], s_acc[f][r]);
#pragma unroll
  for (int dd = 1; dd < 16; dd <<= 1)
#pragma unroll
    for (int r = 0; r < 4; r++) m[r] = fmaxf(m[r], __shfl_xor(m[r], dd, 64));
  float sum[4] = {0.f, 0.f, 0.f, 0.f};
#pragma unroll
  for (int f = 0; f < 16; f++)
#pragma unroll
    for (int r = 0; r < 4; r++) {
      float p = __expf(s_acc[f][r] - m[r]);
      s_acc[f][r] = p;
      sum[r] += p;
    }
#pragma unroll
  for (int dd = 1; dd < 16; dd <<= 1)
#pragma unroll
    for (int r = 0; r < 4; r++) sum[r] += __shfl_xor(sum[r], dd, 64);
  float rs[4];
#pragma unroll
  for (int r = 0; r < 4; r++) rs[r] = 1.f / sum[r];

  // P (unnormalized exp) to LDS bf16; normalization folded into O epilogue
#pragma unroll
  for (int f = 0; f < 16; f++)
#pragma unroll
    for (int r = 0; r < 4; r++)
      Ps[(w * 16 + lg * 4 + r) * 264 + f * 16 + lr] = f2bf(s_acc[f][r]);

  f32x4 o_acc[8];
#pragma unroll
  for (int j = 0; j < 8; j++) o_acc[j] = (f32x4){0.f, 0.f, 0.f, 0.f};

  for (int ct = 0; ct < 4; ct++) {
    __syncthreads();  // all waves past S-phase / previous PV reads of KVs
#pragma unroll
    for (int u = 0; u < 4; u++) {
      int i = tid + u * 256;
      int r = i >> 3, c = i & 7;
      *(i32x4*)&KVs[r * 72 + c * 8] =
          *(const i32x4*)(vT + ((size_t)nmh * 128 + r) * 256 + ct * 64 + c * 8);
    }
    __syncthreads();
#pragma unroll
    for (int kk = 0; kk < 2; kk++) {
      short8 ap = *(const short8*)&Ps[(w * 16 + lr) * 264 + ct * 64 + kk * 32 + lg * 8];
#pragma unroll
      for (int j = 0; j < 8; j++) {
        short8 bv = *(const short8*)&KVs[(j * 16 + lr) * 72 + kk * 32 + lg * 8];
        o_acc[j] = __builtin_amdgcn_mfma_f32_16x16x32_bf16(ap, bv, o_acc[j], 0, 0, 0);
      }
    }
  }

  int nm = nmh >> 3, h = nmh & 7;
  int trow0 = qb * 64 + w * 16;
#pragma unroll
  for (int j = 0; j < 8; j++)
#pragma unroll
    for (int r = 0; r < 4; r++) {
      int t = trow0 + lg * 4 + r;
      int d = h * 128 + j * 16 + lr;
      ao[((size_t)nm * 256 + t) * 1024 + d] = f2bf(o_acc[j][r] * rs[r]);
    }
}

// ---------------- residual + reshape + hi/lo split ----------------
__global__ __launch_bounds__(256) void x2split_kernel(const float* __restrict__ x,
                                                      const ushort* __restrict__ proj,
                                                      ushort* __restrict__ hi,
                                                      ushort* __restrict__ lo) {
  __shared__ ushort sl[64][65];  // [t_local][cv_local]
  int nm = blockIdx.y;
  int tb = blockIdx.x & 3, cvb = blockIdx.x >> 2;
  int t0 = tb * 64, cv0 = cvb * 64;
  int tx = threadIdx.x & 63, ty = threadIdx.x >> 6;
#pragma unroll
  for (int s = 0; s < 16; s++) {
    int r = ty + s * 4;  // t_local
    sl[r][tx] = proj[((size_t)nm * 256 + t0 + r) * 1024 + cv0 + tx];
  }
  __syncthreads();
#pragma unroll
  for (int s = 0; s < 16; s++) {
    int cvl = ty + s * 4;
    size_t R = (size_t)nm * 960 + cv0 + cvl;
    float v = x[R * 256 + t0 + tx] + bf2f(sl[tx][cvl]);
    ushort h = f2bf(v);
    hi[R * 256 + t0 + tx] = h;
    lo[R * 256 + t0 + tx] = f2bf(v - bf2f(h));
  }
}

extern "C" void kernel_launch(void* const* d_in, const int* in_sizes, int n_in,
                              void* d_out, int out_size, void* d_ws, size_t ws_size,
                              hipStream_t stream) {
  const float* x = (const float*)d_in[0];
  const float* ln_g = (const float*)d_in[1];
  const float* ln_b = (const float*)d_in[2];
  const float* w_qkv = (const float*)d_in[3];
  const float* w_out = (const float*)d_in[4];
  const float* b_out = (const float*)d_in[5];
  const float* w_lin = (const float*)d_in[6];
  const float* b_lin = (const float*)d_in[7];
  float* out = (float*)d_out;

  char* ws = (char*)d_ws;
  size_t off = 0;
  auto alloc = [&](size_t bytes) -> void* {
    void* p = ws + off;
    off = (off + bytes + 255) & ~(size_t)255;
    return p;
  };

  ushort* wqkvT = (ushort*)alloc((size_t)3072 * 960 * 2);
  ushort* woutT = (ushort*)alloc((size_t)1024 * 1024 * 2);
  ushort* whi   = (ushort*)alloc((size_t)65536 * 2);
  ushort* wlo   = (ushort*)alloc((size_t)65536 * 2);
  float*  part  = (float*)alloc((size_t)128 * 4 * 256 * 2 * 4);
  float*  stat  = (float*)alloc((size_t)32768 * 2 * 4);
  ushort* xn    = (ushort*)alloc((size_t)32768 * 960 * 2);
  ushort* qbuf  = (ushort*)alloc((size_t)1024 * 256 * 128 * 2);
  ushort* kbuf  = (ushort*)alloc((size_t)1024 * 256 * 128 * 2);
  ushort* vTbuf = (ushort*)alloc((size_t)1024 * 256 * 128 * 2);
  ushort* attnout = (ushort*)alloc((size_t)32768 * 1024 * 2);
  // region reuse after attention is done:
  ushort* proj = qbuf;   // 64 MB needed, 64 MB available
  ushort* x2hi = kbuf;   // 60 MB needed
  ushort* x2lo = vTbuf;  // 60 MB needed

  wtrans_kernel<<<dim3(96, 30), 256, 0, stream>>>(w_qkv, wqkvT, 960, 3072);
  wtrans_kernel<<<dim3(32, 32), 256, 0, stream>>>(w_out, woutT, 1024, 960);
  wsplit_kernel<<<dim3(256), 256, 0, stream>>>(w_lin, whi, wlo, 65536);

  ln_part_kernel<<<dim3(4, 128), 256, 0, stream>>>(x, part);
  ln_stat_kernel<<<dim3(128), 256, 0, stream>>>(part, stat);
  ln_apply_kernel<<<dim3(60, 128), 256, 0, stream>>>(x, stat, ln_g, ln_b, xn);

  gemm_bt<0><<<dim3(24, 256), 256, 0, stream>>>(xn, 960, wqkvT, 960, 30, nullptr, nullptr,
                                                qbuf, kbuf, vTbuf, nullptr, nullptr);
  attn_kernel<<<dim3(4, 1024), 256, 0, stream>>>(qbuf, kbuf, vTbuf, attnout);
  gemm_bt<1><<<dim3(8, 256), 256, 0, stream>>>(attnout, 1024, woutT, 1024, 32, nullptr, nullptr,
                                               proj, nullptr, nullptr, b_out, nullptr);
  x2split_kernel<<<dim3(60, 128), 256, 0, stream>>>(x, proj, x2hi, x2lo);
  gemm_bt<2><<<dim3(2, 960), 256, 0, stream>>>(x2hi, 256, whi, 256, 24, x2lo, wlo,
                                               nullptr, nullptr, nullptr, b_lin, out);
}

// Round 2
// 826.671 us; speedup vs baseline: 1.0445x; 1.0445x over previous
//
#include <hip/hip_runtime.h>

typedef unsigned short ushort;
using short8 = __attribute__((ext_vector_type(8))) short;
using f32x4  = __attribute__((ext_vector_type(4))) float;
using i32x4  = __attribute__((ext_vector_type(4))) int;

static __device__ __forceinline__ float bf2f(ushort u) {
  union { unsigned int i; float f; } x; x.i = ((unsigned int)u) << 16; return x.f;
}
static __device__ __forceinline__ ushort f2bf(float f) {
  union { float f; unsigned int i; } x; x.f = f;
  unsigned int u = x.i;
  unsigned int r = u + 0x7fffu + ((u >> 16) & 1u);
  return (ushort)(r >> 16);
}

// async global -> LDS, 16B per lane; LDS dest is wave-uniform base + lane*16
#define GLOAD16(gp, lp)                                                   \
  __builtin_amdgcn_global_load_lds(                                      \
      (const __attribute__((address_space(1))) void*)(gp),               \
      (__attribute__((address_space(3))) void*)(lp), 16, 0, 0)

// ---------------- weight prep ----------------
// out[c][r] = bf16(in[r][c]) for c < C, 0 for C <= c < Cout (grid.x*32). R % 32 == 0.
__global__ __launch_bounds__(256) void wtrans_kernel(const float* __restrict__ in,
                                                     ushort* __restrict__ out,
                                                     int R, int C) {
  __shared__ float sl[32][33];
  int tx = threadIdx.x & 31, ty = threadIdx.x >> 5;  // ty 0..7
  int c0 = blockIdx.x * 32, r0 = blockIdx.y * 32;
#pragma unroll
  for (int s = 0; s < 4; s++) {
    int r = r0 + ty + s * 8;
    int c = c0 + tx;
    sl[ty + s * 8][tx] = (c < C) ? in[(size_t)r * C + c] : 0.f;
  }
  __syncthreads();
#pragma unroll
  for (int s = 0; s < 4; s++) {
    int c = c0 + ty + s * 8;
    int r = r0 + tx;
    out[(size_t)c * R + r] = f2bf(sl[tx][ty + s * 8]);
  }
}

__global__ void wsplit_kernel(const float* __restrict__ in, ushort* __restrict__ hi,
                              ushort* __restrict__ lo, int n) {
  int i = blockIdx.x * 256 + threadIdx.x;
  if (i < n) {
    float v = in[i];
    ushort h = f2bf(v);
    hi[i] = h;
    lo[i] = f2bf(v - bf2f(h));
  }
}

// ---------------- LayerNorm (over dim=960 for each (nm,t)) ----------------
__global__ __launch_bounds__(256) void ln_part_kernel(const float* __restrict__ x,
                                                      float* __restrict__ part) {
  int nm = blockIdx.y, ch = blockIdx.x, t = threadIdx.x;
  float s = 0.f, ss = 0.f;
  const float* base = x + ((size_t)nm * 960 + (size_t)ch * 240) * 256 + t;
#pragma unroll 4
  for (int r = 0; r < 240; r++) {
    float v = base[(size_t)r * 256];
    s += v; ss += v * v;
  }
  float2 o; o.x = s; o.y = ss;
  ((float2*)part)[(nm * 4 + ch) * 256 + t] = o;
}

__global__ __launch_bounds__(256) void ln_stat_kernel(const float* __restrict__ part,
                                                      float* __restrict__ stat) {
  int nm = blockIdx.x, t = threadIdx.x;
  float s = 0.f, ss = 0.f;
#pragma unroll
  for (int ch = 0; ch < 4; ch++) {
    float2 p = ((const float2*)part)[(nm * 4 + ch) * 256 + t];
    s += p.x; ss += p.y;
  }
  float mean = s * (1.f / 960.f);
  float var = ss * (1.f / 960.f) - mean * mean;
  float2 o; o.x = mean; o.y = rsqrtf(var + 1e-5f);
  ((float2*)stat)[nm * 256 + t] = o;
}

// K1c: tiled transpose + normalize -> xn bf16 [nm*256+t][960]
__global__ __launch_bounds__(256) void ln_apply_kernel(const float* __restrict__ x,
                                                       const float* __restrict__ stat,
                                                       const float* __restrict__ g,
                                                       const float* __restrict__ b,
                                                       ushort* __restrict__ xn) {
  __shared__ float sl[64][65];
  int nm = blockIdx.y;
  int tb = blockIdx.x & 3, cvb = blockIdx.x >> 2;
  int t0 = tb * 64, cv0 = cvb * 64;
  int tx = threadIdx.x & 63, ty = threadIdx.x >> 6;
#pragma unroll
  for (int s = 0; s < 16; s++) {
    int r = ty + s * 4;  // cv_local
    sl[r][tx] = x[((size_t)nm * 960 + cv0 + r) * 256 + t0 + tx];
  }
  __syncthreads();
  float gg = g[cv0 + tx], bb = b[cv0 + tx];
#pragma unroll
  for (int s = 0; s < 16; s++) {
    int tt = ty + s * 4;  // t_local
    float2 ms = ((const float2*)stat)[nm * 256 + t0 + tt];
    float v = (sl[tx][tt] - ms.x) * ms.y * gg + bb;
    xn[((size_t)nm * 256 + t0 + tt) * 960 + cv0 + tx] = f2bf(v);
  }
}

// ---------------- generic bf16 MFMA GEMM, C = A @ B  (B given transposed: BT[col][k]) ----
// 128x128 tile, BK=32, 4 waves (2x2), each wave 64x64 (4x4 frags of 16x16x32).
// m97 structure: global_load_lds width-16 staging into LINEAR [128][32] LDS tiles.
// MODE 0: QKV epilogue (scatter q*scale, k, vT)
// MODE 1: out-proj epilogue (bf16 proj + b_out)
// MODE 2: final 3-segment split-bf16 (A,BT / A,Blo / Alo,BT), tanh + b_lin -> f32 out
template <int MODE>
__global__ __launch_bounds__(256) void gemm_bt(
    const ushort* __restrict__ A, int lda, const ushort* __restrict__ BT, int ldb, int nkt,
    const ushort* __restrict__ Alo, const ushort* __restrict__ Blo,
    ushort* __restrict__ o0, ushort* __restrict__ o1, ushort* __restrict__ o2,
    const float* __restrict__ bias, float* __restrict__ fout) {
  __shared__ ushort Ash[128 * 32];
  __shared__ ushort Bsh[128 * 32];
  int tid = threadIdx.x;
  int l = tid & 63, w = tid >> 6;
  int wr = w >> 1, wc = w & 1;
  int lr = l & 15, lg = l >> 4;
  int cb = blockIdx.x * 128, rb = blockIdx.y * 128;

  // staging granule for this lane: g = w*128 + u*64 + l, u in {0,1}
  // linear layout: granule g -> row g>>2, col-granule g&3 (8 elems each)
  int g0 = w * 128 + l;
  int srow = g0 >> 2, scg = g0 & 3;  // u=1 is srow+16, same scg

  f32x4 acc[4][4];
#pragma unroll
  for (int i = 0; i < 4; i++)
#pragma unroll
    for (int j = 0; j < 4; j++) acc[i][j] = (f32x4){0.f, 0.f, 0.f, 0.f};

  for (int kt = 0; kt < nkt; kt++) {
    const ushort* Ap;
    const ushort* Bp;
    int k0;
    if (MODE == 2) {
      int seg = kt >> 3;
      k0 = (kt & 7) * 32;
      Ap = (seg == 2) ? Alo : A;
      Bp = (seg == 1) ? Blo : BT;
    } else {
      Ap = A; Bp = BT; k0 = kt * 32;
    }
    __syncthreads();
    {
      const ushort* As = Ap + (size_t)(rb + srow) * lda + k0 + scg * 8;
      const ushort* Bs = Bp + (size_t)(cb + srow) * ldb + k0 + scg * 8;
      GLOAD16(As, &Ash[w * 1024]);
      GLOAD16(As + (size_t)16 * lda, &Ash[w * 1024 + 512]);
      GLOAD16(Bs, &Bsh[w * 1024]);
      GLOAD16(Bs + (size_t)16 * ldb, &Bsh[w * 1024 + 512]);
    }
    __syncthreads();
    short8 a[4], b[4];
#pragma unroll
    for (int i = 0; i < 4; i++)
      a[i] = *(const short8*)&Ash[(wr * 64 + i * 16 + lr) * 32 + lg * 8];
#pragma unroll
    for (int j = 0; j < 4; j++)
      b[j] = *(const short8*)&Bsh[(wc * 64 + j * 16 + lr) * 32 + lg * 8];
#pragma unroll
    for (int i = 0; i < 4; i++)
#pragma unroll
      for (int j = 0; j < 4; j++)
        acc[i][j] = __builtin_amdgcn_mfma_f32_16x16x32_bf16(a[i], b[j], acc[i][j], 0, 0, 0);
  }

  int row0 = rb + wr * 64, col0 = cb + wc * 64;
#pragma unroll
  for (int i = 0; i < 4; i++) {
#pragma unroll
    for (int j = 0; j < 4; j++) {
      f32x4 v = acc[i][j];
#pragma unroll
      for (int r = 0; r < 4; r++) {
        int row = row0 + i * 16 + lg * 4 + r;
        int col = col0 + j * 16 + lr;
        float val = v[r];
        if (MODE == 0) {
          int nm = row >> 8, t = row & 255;
          int which = col >> 10, cl = col & 1023;
          int h = cl >> 7, d = cl & 127;
          int nmh = nm * 8 + h;
          if (which == 0)
            o0[((size_t)nmh * 256 + t) * 128 + d] = f2bf(val * 0.08838834764831845f);
          else if (which == 1)
            o1[((size_t)nmh * 256 + t) * 128 + d] = f2bf(val);
          else
            o2[((size_t)nmh * 128 + d) * 256 + t] = f2bf(val);  // V^T
        } else if (MODE == 1) {
          float bb = (col < 960) ? bias[col] : 0.f;
          o0[(size_t)row * 1024 + col] = f2bf(val + bb);
        } else {
          fout[(size_t)row * 256 + col] = tanhf(val + bias[col]);
        }
      }
    }
  }
}

// ---------------- fused attention: 64 q-rows per block, full T=256 in regs ----------------
__global__ __launch_bounds__(256) void attn_kernel(const ushort* __restrict__ q,
                                                   const ushort* __restrict__ kb,
                                                   const ushort* __restrict__ vT,
                                                   ushort* __restrict__ ao) {
  __shared__ ushort KVs[128 * 72];  // K tile [64][136] or vT tile [128][72] (time-shared)
  __shared__ ushort Ps[64 * 264];   // P tile [64 rows][256 cols], stride 264
  int tid = threadIdx.x;
  int l = tid & 63, w = tid >> 6;
  int lr = l & 15, lg = l >> 4;
  int qb = blockIdx.x;   // 0..3
  int nmh = blockIdx.y;  // 0..1023

  // Q fragments straight from global (q pre-scaled by 1/sqrt(D))
  short8 aq[4];
  {
    const ushort* qp = q + ((size_t)nmh * 256 + qb * 64 + w * 16 + lr) * 128 + lg * 8;
#pragma unroll
    for (int kk = 0; kk < 4; kk++) aq[kk] = *(const short8*)(qp + kk * 32);
  }

  f32x4 s_acc[16];
#pragma unroll
  for (int f = 0; f < 16; f++) s_acc[f] = (f32x4){0.f, 0.f, 0.f, 0.f};

  for (int ct = 0; ct < 4; ct++) {
    __syncthreads();
#pragma unroll
    for (int u = 0; u < 4; u++) {
      int i = tid + u * 256;
      int r = i >> 4, c = i & 15;
      *(i32x4*)&KVs[r * 136 + c * 8] =
          *(const i32x4*)(kb + ((size_t)nmh * 256 + ct * 64 + r) * 128 + c * 8);
    }
    __syncthreads();
#pragma unroll
    for (int j = 0; j < 4; j++) {
      short8 bk[4];
#pragma unroll
      for (int kk = 0; kk < 4; kk++)
        bk[kk] = *(const short8*)&KVs[(j * 16 + lr) * 136 + kk * 32 + lg * 8];
#pragma unroll
      for (int kk = 0; kk < 4; kk++)
        s_acc[ct * 4 + j] =
            __builtin_amdgcn_mfma_f32_16x16x32_bf16(aq[kk], bk[kk], s_acc[ct * 4 + j], 0, 0, 0);
    }
  }

  // softmax over each row (rows live in lanes lg, regs r; cols across lr and 16 frags)
  float m[4] = {-1e30f, -1e30f, -1e30f, -1e30f};
#pragma unroll
  for (int f = 0; f < 16; f++)
#pragma unroll
    for (int r = 0; r < 4; r++) m[r] = fmaxf(m[r], s_acc[f][r]);
#pragma unroll
  for (int dd = 1; dd < 16; dd <<= 1)
#pragma unroll
    for (int r = 0; r < 4; r++) m[r] = fmaxf(m[r], __shfl_xor(m[r], dd, 64));
  float sum[4] = {0.f, 0.f, 0.f, 0.f};
#pragma unroll
  for (int f = 0; f < 16; f++)
#pragma unroll
    for (int r = 0; r < 4; r++) {
      float p = __expf(s_acc[f][r] - m[r]);
      s_acc[f][r] = p;
      sum[r] += p;
    }
#pragma unroll
  for (int dd = 1; dd < 16; dd <<= 1)
#pragma unroll
    for (int r = 0; r < 4; r++) sum[r] += __shfl_xor(sum[r], dd, 64);
  float rs[4];
#pragma unroll
  for (int r = 0; r < 4; r++) rs[r] = 1.f / sum[r];

  // P (unnormalized exp) to LDS bf16; normalization folded into O epilogue
#pragma unroll
  for (int f = 0; f < 16; f++)
#pragma unroll
    for (int r = 0; r < 4; r++)
      Ps[(w * 16 + lg * 4 + r) * 264 + f * 16 + lr] = f2bf(s_acc[f][r]);

  f32x4 o_acc[8];
#pragma unroll
  for (int j = 0; j < 8; j++) o_acc[j] = (f32x4){0.f, 0.f, 0.f, 0.f};

  for (int ct = 0; ct < 4; ct++) {
    __syncthreads();  // all waves past S-phase / previous PV reads of KVs
#pragma unroll
    for (int u = 0; u < 4; u++) {
      int i = tid + u * 256;
      int r = i >> 3, c = i & 7;
      *(i32x4*)&KVs[r * 72 + c * 8] =
          *(const i32x4*)(vT + ((size_t)nmh * 128 + r) * 256 + ct * 64 + c * 8);
    }
    __syncthreads();
#pragma unroll
    for (int kk = 0; kk < 2; kk++) {
      short8 ap = *(const short8*)&Ps[(w * 16 + lr) * 264 + ct * 64 + kk * 32 + lg * 8];
#pragma unroll
      for (int j = 0; j < 8; j++) {
        short8 bv = *(const short8*)&KVs[(j * 16 + lr) * 72 + kk * 32 + lg * 8];
        o_acc[j] = __builtin_amdgcn_mfma_f32_16x16x32_bf16(ap, bv, o_acc[j], 0, 0, 0);
      }
    }
  }

  int nm = nmh >> 3, h = nmh & 7;
  int trow0 = qb * 64 + w * 16;
#pragma unroll
  for (int j = 0; j < 8; j++)
#pragma unroll
    for (int r = 0; r < 4; r++) {
      int t = trow0 + lg * 4 + r;
      int d = h * 128 + j * 16 + lr;
      ao[((size_t)nm * 256 + t) * 1024 + d] = f2bf(o_acc[j][r] * rs[r]);
    }
}

// ---------------- residual + reshape + hi/lo split ----------------
__global__ __launch_bounds__(256) void x2split_kernel(const float* __restrict__ x,
                                                      const ushort* __restrict__ proj,
                                                      ushort* __restrict__ hi,
                                                      ushort* __restrict__ lo) {
  __shared__ ushort sl[64][65];  // [t_local][cv_local]
  int nm = blockIdx.y;
  int tb = blockIdx.x & 3, cvb = blockIdx.x >> 2;
  int t0 = tb * 64, cv0 = cvb * 64;
  int tx = threadIdx.x & 63, ty = threadIdx.x >> 6;
#pragma unroll
  for (int s = 0; s < 16; s++) {
    int r = ty + s * 4;  // t_local
    sl[r][tx] = proj[((size_t)nm * 256 + t0 + r) * 1024 + cv0 + tx];
  }
  __syncthreads();
#pragma unroll
  for (int s = 0; s < 16; s++) {
    int cvl = ty + s * 4;
    size_t R = (size_t)nm * 960 + cv0 + cvl;
    float v = x[R * 256 + t0 + tx] + bf2f(sl[tx][cvl]);
    ushort h = f2bf(v);
    hi[R * 256 + t0 + tx] = h;
    lo[R * 256 + t0 + tx] = f2bf(v - bf2f(h));
  }
}

extern "C" void kernel_launch(void* const* d_in, const int* in_sizes, int n_in,
                              void* d_out, int out_size, void* d_ws, size_t ws_size,
                              hipStream_t stream) {
  const float* x = (const float*)d_in[0];
  const float* ln_g = (const float*)d_in[1];
  const float* ln_b = (const float*)d_in[2];
  const float* w_qkv = (const float*)d_in[3];
  const float* w_out = (const float*)d_in[4];
  const float* b_out = (const float*)d_in[5];
  const float* w_lin = (const float*)d_in[6];
  const float* b_lin = (const float*)d_in[7];
  float* out = (float*)d_out;

  char* ws = (char*)d_ws;
  size_t off = 0;
  auto alloc = [&](size_t bytes) -> void* {
    void* p = ws + off;
    off = (off + bytes + 255) & ~(size_t)255;
    return p;
  };

  ushort* wqkvT = (ushort*)alloc((size_t)3072 * 960 * 2);
  ushort* woutT = (ushort*)alloc((size_t)1024 * 1024 * 2);
  ushort* whi   = (ushort*)alloc((size_t)65536 * 2);
  ushort* wlo   = (ushort*)alloc((size_t)65536 * 2);
  float*  part  = (float*)alloc((size_t)128 * 4 * 256 * 2 * 4);
  float*  stat  = (float*)alloc((size_t)32768 * 2 * 4);
  ushort* xn    = (ushort*)alloc((size_t)32768 * 960 * 2);
  ushort* qbuf  = (ushort*)alloc((size_t)1024 * 256 * 128 * 2);
  ushort* kbuf  = (ushort*)alloc((size_t)1024 * 256 * 128 * 2);
  ushort* vTbuf = (ushort*)alloc((size_t)1024 * 256 * 128 * 2);
  ushort* attnout = (ushort*)alloc((size_t)32768 * 1024 * 2);
  // region reuse after attention is done:
  ushort* proj = qbuf;   // 64 MB needed, 64 MB available
  ushort* x2hi = kbuf;   // 60 MB needed
  ushort* x2lo = vTbuf;  // 60 MB needed

  wtrans_kernel<<<dim3(96, 30), 256, 0, stream>>>(w_qkv, wqkvT, 960, 3072);
  wtrans_kernel<<<dim3(32, 32), 256, 0, stream>>>(w_out, woutT, 1024, 960);
  wsplit_kernel<<<dim3(256), 256, 0, stream>>>(w_lin, whi, wlo, 65536);

  ln_part_kernel<<<dim3(4, 128), 256, 0, stream>>>(x, part);
  ln_stat_kernel<<<dim3(128), 256, 0, stream>>>(part, stat);
  ln_apply_kernel<<<dim3(60, 128), 256, 0, stream>>>(x, stat, ln_g, ln_b, xn);

  gemm_bt<0><<<dim3(24, 256), 256, 0, stream>>>(xn, 960, wqkvT, 960, 30, nullptr, nullptr,
                                                qbuf, kbuf, vTbuf, nullptr, nullptr);
  attn_kernel<<<dim3(4, 1024), 256, 0, stream>>>(qbuf, kbuf, vTbuf, attnout);
  gemm_bt<1><<<dim3(8, 256), 256, 0, stream>>>(attnout, 1024, woutT, 1024, 32, nullptr, nullptr,
                                               proj, nullptr, nullptr, b_out, nullptr);
  x2split_kernel<<<dim3(60, 128), 256, 0, stream>>>(x, proj, x2hi, x2lo);
  gemm_bt<2><<<dim3(2, 960), 256, 0, stream>>>(x2hi, 256, whi, 256, 24, x2lo, wlo,
                                               nullptr, nullptr, nullptr, b_lin, out);
}

// Round 3
// 694.372 us; speedup vs baseline: 1.2435x; 1.1905x over previous
//
#include <hip/hip_runtime.h>

typedef unsigned short ushort;
using short8 = __attribute__((ext_vector_type(8))) short;
using f32x4  = __attribute__((ext_vector_type(4))) float;
using i32x4  = __attribute__((ext_vector_type(4))) int;
using us4    = __attribute__((ext_vector_type(4))) ushort;

static __device__ __forceinline__ float bf2f(ushort u) {
  union { unsigned int i; float f; } x; x.i = ((unsigned int)u) << 16; return x.f;
}
static __device__ __forceinline__ ushort f2bf(float f) {
  union { float f; unsigned int i; } x; x.f = f;
  unsigned int u = x.i;
  unsigned int r = u + 0x7fffu + ((u >> 16) & 1u);
  return (ushort)(r >> 16);
}

// async global -> LDS, 16B per lane; LDS dest is wave-uniform base + lane*16
#define GLOAD16(gp, lp)                                                   \
  __builtin_amdgcn_global_load_lds(                                      \
      (const __attribute__((address_space(1))) void*)(gp),               \
      (__attribute__((address_space(3))) void*)(lp), 16, 0, 0)

// ---------------- weight prep ----------------
__global__ __launch_bounds__(256) void wtrans_kernel(const float* __restrict__ in,
                                                     ushort* __restrict__ out,
                                                     int R, int C) {
  __shared__ float sl[32][33];
  int tx = threadIdx.x & 31, ty = threadIdx.x >> 5;
  int c0 = blockIdx.x * 32, r0 = blockIdx.y * 32;
#pragma unroll
  for (int s = 0; s < 4; s++) {
    int r = r0 + ty + s * 8;
    int c = c0 + tx;
    sl[ty + s * 8][tx] = (c < C) ? in[(size_t)r * C + c] : 0.f;
  }
  __syncthreads();
#pragma unroll
  for (int s = 0; s < 4; s++) {
    int c = c0 + ty + s * 8;
    int r = r0 + tx;
    out[(size_t)c * R + r] = f2bf(sl[tx][ty + s * 8]);
  }
}

__global__ void wsplit_kernel(const float* __restrict__ in, ushort* __restrict__ hi,
                              ushort* __restrict__ lo, int n) {
  int i = blockIdx.x * 256 + threadIdx.x;
  if (i < n) {
    float v = in[i];
    ushort h = f2bf(v);
    hi[i] = h;
    lo[i] = f2bf(v - bf2f(h));
  }
}

// ---------------- LayerNorm ----------------
__global__ __launch_bounds__(256) void ln_part_kernel(const float* __restrict__ x,
                                                      float* __restrict__ part) {
  int nm = blockIdx.y, ch = blockIdx.x, t = threadIdx.x;
  float s = 0.f, ss = 0.f;
  const float* base = x + ((size_t)nm * 960 + (size_t)ch * 240) * 256 + t;
#pragma unroll 4
  for (int r = 0; r < 240; r++) {
    float v = base[(size_t)r * 256];
    s += v; ss += v * v;
  }
  float2 o; o.x = s; o.y = ss;
  ((float2*)part)[(nm * 4 + ch) * 256 + t] = o;
}

__global__ __launch_bounds__(256) void ln_stat_kernel(const float* __restrict__ part,
                                                      float* __restrict__ stat) {
  int nm = blockIdx.x, t = threadIdx.x;
  float s = 0.f, ss = 0.f;
#pragma unroll
  for (int ch = 0; ch < 4; ch++) {
    float2 p = ((const float2*)part)[(nm * 4 + ch) * 256 + t];
    s += p.x; ss += p.y;
  }
  float mean = s * (1.f / 960.f);
  float var = ss * (1.f / 960.f) - mean * mean;
  float2 o; o.x = mean; o.y = rsqrtf(var + 1e-5f);
  ((float2*)stat)[nm * 256 + t] = o;
}

__global__ __launch_bounds__(256) void ln_apply_kernel(const float* __restrict__ x,
                                                       const float* __restrict__ stat,
                                                       const float* __restrict__ g,
                                                       const float* __restrict__ b,
                                                       ushort* __restrict__ xn) {
  __shared__ float sl[64][65];
  int nm = blockIdx.y;
  int tb = blockIdx.x & 3, cvb = blockIdx.x >> 2;
  int t0 = tb * 64, cv0 = cvb * 64;
  int tx = threadIdx.x & 63, ty = threadIdx.x >> 6;
#pragma unroll
  for (int s = 0; s < 16; s++) {
    int r = ty + s * 4;
    sl[r][tx] = x[((size_t)nm * 960 + cv0 + r) * 256 + t0 + tx];
  }
  __syncthreads();
  float gg = g[cv0 + tx], bb = b[cv0 + tx];
#pragma unroll
  for (int s = 0; s < 16; s++) {
    int tt = ty + s * 4;
    float2 ms = ((const float2*)stat)[nm * 256 + t0 + tt];
    float v = (sl[tx][tt] - ms.x) * ms.y * gg + bb;
    xn[((size_t)nm * 256 + t0 + tt) * 960 + cv0 + tx] = f2bf(v);
  }
}

// ---------------- 256x256 tile GEMM, BK=32, 8 waves, counted-vmcnt dbuf pipeline ----
// LDS 64KB: A[2][256][32] @0, B[2][256][32] @32768 (bytes). Both-sides XOR swizzle:
// logical col-slot s of row r lives at physical slot s ^ ((r>>1)&3) (16B slots).
// Staging: gload_lds linear dest; SOURCE col pre-swizzled. Reads: addr-swizzled.
// MODE 0: QKV epilogue (scatter q*scale, k, vT packed 8B)
// MODE 1: out-proj epilogue (bf16 proj + b_out)
// MODE 2: final 3-segment split-bf16, tanh + b_lin -> f32 out
template <int MODE>
__global__ __launch_bounds__(512, 2) void gemm256(
    const ushort* __restrict__ A, int lda, const ushort* __restrict__ BT, int ldb, int nkt,
    const ushort* __restrict__ Alo, const ushort* __restrict__ Blo,
    ushort* __restrict__ o0, ushort* __restrict__ o1, ushort* __restrict__ o2,
    const float* __restrict__ bias, float* __restrict__ fout) {
  __shared__ char smem[65536];
  int tid = threadIdx.x;
  int l = tid & 63, w = tid >> 6;
  int wr = w >> 2, wc = w & 3;        // wave tile: rows [wr*128,+128), cols [wc*64,+64)
  int lr = l & 15, lg = l >> 4;
  int cb = blockIdx.x * 256, rb = blockIdx.y * 256;

  // staging constants (per thread, constant across tiles and halves)
  int sr = tid >> 2;                                  // row within half-tile 0..127
  int sl_ = ((tid & 3) ^ ((tid >> 3) & 3)) * 8;       // pre-swizzled source col (elems)
  char* ldsA0 = smem + w * 1024;                      // + buf*16384 + u*8192
  char* ldsB0 = smem + 32768 + w * 1024;

  // fragment-read bases (swizzled)
  int swz = (lg ^ ((lr >> 1) & 3)) << 4;
  const char* ArdB = smem + (wr * 128 + lr) * 64 + swz;          // + buf*16384 + i*1024
  const char* BrdB = smem + 32768 + (wc * 64 + lr) * 64 + swz;   // + buf*16384 + j*1024

  auto stage = [&](int kt, int buf) {
    const ushort* Ap; const ushort* Bp; int k0;
    if (MODE == 2) {
      int seg = kt >> 3; k0 = (kt & 7) * 32;
      Ap = (seg == 2) ? Alo : A;
      Bp = (seg == 1) ? Blo : BT;
    } else { Ap = A; Bp = BT; k0 = kt * 32; }
    const ushort* ga = Ap + (size_t)(rb + sr) * lda + k0 + sl_;
    const ushort* gb = Bp + (size_t)(cb + sr) * ldb + k0 + sl_;
    GLOAD16(ga,                     ldsA0 + buf * 16384);
    GLOAD16(ga + (size_t)128 * lda, ldsA0 + buf * 16384 + 8192);
    GLOAD16(gb,                     ldsB0 + buf * 16384);
    GLOAD16(gb + (size_t)128 * ldb, ldsB0 + buf * 16384 + 8192);
  };

  f32x4 acc[8][4];
#pragma unroll
  for (int i = 0; i < 8; i++)
#pragma unroll
    for (int j = 0; j < 4; j++) acc[i][j] = (f32x4){0.f, 0.f, 0.f, 0.f};

  stage(0, 0);
  stage(1, 1);
  asm volatile("s_waitcnt vmcnt(4)" ::: "memory");  // tile0 done, tile1 in flight
  __builtin_amdgcn_s_barrier();

  for (int t = 0; t < nkt; t++) {
    int buf = t & 1;
    const char* Ard = ArdB + buf * 16384;
    const char* Brd = BrdB + buf * 16384;
    short8 a[8], b[4];
#pragma unroll
    for (int j = 0; j < 4; j++) b[j] = *(const short8*)(Brd + j * 1024);
#pragma unroll
    for (int i = 0; i < 8; i++) a[i] = *(const short8*)(Ard + i * 1024);
    asm volatile("s_waitcnt lgkmcnt(0)" ::: "memory");  // frags in regs
    __builtin_amdgcn_sched_barrier(0);
    __builtin_amdgcn_s_barrier();                        // all waves done reading buf
    if (t + 2 < nkt) stage(t + 2, buf);                  // overwrite buf; overlaps MFMA
    __builtin_amdgcn_s_setprio(1);
#pragma unroll
    for (int i = 0; i < 8; i++)
#pragma unroll
      for (int j = 0; j < 4; j++)
        acc[i][j] = __builtin_amdgcn_mfma_f32_16x16x32_bf16(a[i], b[j], acc[i][j], 0, 0, 0);
    __builtin_amdgcn_s_setprio(0);
    __builtin_amdgcn_sched_barrier(0);
    if (t + 1 < nkt) {
      if (t + 2 < nkt) asm volatile("s_waitcnt vmcnt(4)" ::: "memory");  // tile t+1 done
      else             asm volatile("s_waitcnt vmcnt(0)" ::: "memory");
      __builtin_amdgcn_s_barrier();
    }
  }

  int row0 = rb + wr * 128, col0 = cb + wc * 64;
  if (MODE == 0) {
    int nm = rb >> 8;          // block covers exactly one nm (256 rows)
    int which = cb >> 10;      // uniform per block (1024 % 256 == 0)
#pragma unroll
    for (int i = 0; i < 8; i++)
#pragma unroll
      for (int j = 0; j < 4; j++) {
        f32x4 v = acc[i][j];
        int col = col0 + j * 16 + lr;
        int cl = col & 1023;
        int h = cl >> 7, d = cl & 127;
        int nmh = nm * 8 + h;
        int t0 = wr * 128 + i * 16 + lg * 4;
        if (which == 2) {
          us4 pk;
          pk.x = f2bf(v[0]); pk.y = f2bf(v[1]); pk.z = f2bf(v[2]); pk.w = f2bf(v[3]);
          *(us4*)&o2[((size_t)nmh * 128 + d) * 256 + t0] = pk;  // V^T, 8B packed
        } else if (which == 0) {
#pragma unroll
          for (int r = 0; r < 4; r++)
            o0[((size_t)nmh * 256 + t0 + r) * 128 + d] = f2bf(v[r] * 0.08838834764831845f);
        } else {
#pragma unroll
          for (int r = 0; r < 4; r++)
            o1[((size_t)nmh * 256 + t0 + r) * 128 + d] = f2bf(v[r]);
        }
      }
  } else if (MODE == 1) {
#pragma unroll
    for (int i = 0; i < 8; i++)
#pragma unroll
      for (int j = 0; j < 4; j++) {
        f32x4 v = acc[i][j];
        int col = col0 + j * 16 + lr;
        float bb = (col < 960) ? bias[col] : 0.f;
#pragma unroll
        for (int r = 0; r < 4; r++) {
          int row = row0 + i * 16 + lg * 4 + r;
          o0[(size_t)row * 1024 + col] = f2bf(v[r] + bb);
        }
      }
  } else {
#pragma unroll
    for (int i = 0; i < 8; i++)
#pragma unroll
      for (int j = 0; j < 4; j++) {
        f32x4 v = acc[i][j];
        int col = col0 + j * 16 + lr;
        float bb = bias[col];
#pragma unroll
        for (int r = 0; r < 4; r++) {
          int row = row0 + i * 16 + lg * 4 + r;
          fout[(size_t)row * 256 + col] = tanhf(v[r] + bb);
        }
      }
  }
}

// ---------------- fused attention: 64 q-rows per block, full T=256 in regs ----------------
__global__ __launch_bounds__(256) void attn_kernel(const ushort* __restrict__ q,
                                                   const ushort* __restrict__ kb,
                                                   const ushort* __restrict__ vT,
                                                   ushort* __restrict__ ao) {
  __shared__ ushort KVs[128 * 72];
  __shared__ ushort Ps[64 * 264];
  int tid = threadIdx.x;
  int l = tid & 63, w = tid >> 6;
  int lr = l & 15, lg = l >> 4;
  int qb = blockIdx.x;
  int nmh = blockIdx.y;

  short8 aq[4];
  {
    const ushort* qp = q + ((size_t)nmh * 256 + qb * 64 + w * 16 + lr) * 128 + lg * 8;
#pragma unroll
    for (int kk = 0; kk < 4; kk++) aq[kk] = *(const short8*)(qp + kk * 32);
  }

  f32x4 s_acc[16];
#pragma unroll
  for (int f = 0; f < 16; f++) s_acc[f] = (f32x4){0.f, 0.f, 0.f, 0.f};

  for (int ct = 0; ct < 4; ct++) {
    __syncthreads();
#pragma unroll
    for (int u = 0; u < 4; u++) {
      int i = tid + u * 256;
      int r = i >> 4, c = i & 15;
      *(i32x4*)&KVs[r * 136 + c * 8] =
          *(const i32x4*)(kb + ((size_t)nmh * 256 + ct * 64 + r) * 128 + c * 8);
    }
    __syncthreads();
#pragma unroll
    for (int j = 0; j < 4; j++) {
      short8 bk[4];
#pragma unroll
      for (int kk = 0; kk < 4; kk++)
        bk[kk] = *(const short8*)&KVs[(j * 16 + lr) * 136 + kk * 32 + lg * 8];
#pragma unroll
      for (int kk = 0; kk < 4; kk++)
        s_acc[ct * 4 + j] =
            __builtin_amdgcn_mfma_f32_16x16x32_bf16(aq[kk], bk[kk], s_acc[ct * 4 + j], 0, 0, 0);
    }
  }

  float m[4] = {-1e30f, -1e30f, -1e30f, -1e30f};
#pragma unroll
  for (int f = 0; f < 16; f++)
#pragma unroll
    for (int r = 0; r < 4; r++) m[r] = fmaxf(m[r], s_acc[f][r]);
#pragma unroll
  for (int dd = 1; dd < 16; dd <<= 1)
#pragma unroll
    for (int r = 0; r < 4; r++) m[r] = fmaxf(m[r], __shfl_xor(m[r], dd, 64));
  float sum[4] = {0.f, 0.f, 0.f, 0.f};
#pragma unroll
  for (int f = 0; f < 16; f++)
#pragma unroll
    for (int r = 0; r < 4; r++) {
      float p = __expf(s_acc[f][r] - m[r]);
      s_acc[f][r] = p;
      sum[r] += p;
    }
#pragma unroll
  for (int dd = 1; dd < 16; dd <<= 1)
#pragma unroll
    for (int r = 0; r < 4; r++) sum[r] += __shfl_xor(sum[r], dd, 64);
  float rs[4];
#pragma unroll
  for (int r = 0; r < 4; r++) rs[r] = 1.f / sum[r];

#pragma unroll
  for (int f = 0; f < 16; f++)
#pragma unroll
    for (int r = 0; r < 4; r++)
      Ps[(w * 16 + lg * 4 + r) * 264 + f * 16 + lr] = f2bf(s_acc[f][r]);

  f32x4 o_acc[8];
#pragma unroll
  for (int j = 0; j < 8; j++) o_acc[j] = (f32x4){0.f, 0.f, 0.f, 0.f};

  for (int ct = 0; ct < 4; ct++) {
    __syncthreads();
#pragma unroll
    for (int u = 0; u < 4; u++) {
      int i = tid + u * 256;
      int r = i >> 3, c = i & 7;
      *(i32x4*)&KVs[r * 72 + c * 8] =
          *(const i32x4*)(vT + ((size_t)nmh * 128 + r) * 256 + ct * 64 + c * 8);
    }
    __syncthreads();
#pragma unroll
    for (int kk = 0; kk < 2; kk++) {
      short8 ap = *(const short8*)&Ps[(w * 16 + lr) * 264 + ct * 64 + kk * 32 + lg * 8];
#pragma unroll
      for (int j = 0; j < 8; j++) {
        short8 bv = *(const short8*)&KVs[(j * 16 + lr) * 72 + kk * 32 + lg * 8];
        o_acc[j] = __builtin_amdgcn_mfma_f32_16x16x32_bf16(ap, bv, o_acc[j], 0, 0, 0);
      }
    }
  }

  int nm = nmh >> 3, h = nmh & 7;
  int trow0 = qb * 64 + w * 16;
#pragma unroll
  for (int j = 0; j < 8; j++)
#pragma unroll
    for (int r = 0; r < 4; r++) {
      int t = trow0 + lg * 4 + r;
      int d = h * 128 + j * 16 + lr;
      ao[((size_t)nm * 256 + t) * 1024 + d] = f2bf(o_acc[j][r] * rs[r]);
    }
}

// ---------------- residual + reshape + hi/lo split ----------------
__global__ __launch_bounds__(256) void x2split_kernel(const float* __restrict__ x,
                                                      const ushort* __restrict__ proj,
                                                      ushort* __restrict__ hi,
                                                      ushort* __restrict__ lo) {
  __shared__ ushort sl[64][65];
  int nm = blockIdx.y;
  int tb = blockIdx.x & 3, cvb = blockIdx.x >> 2;
  int t0 = tb * 64, cv0 = cvb * 64;
  int tx = threadIdx.x & 63, ty = threadIdx.x >> 6;
#pragma unroll
  for (int s = 0; s < 16; s++) {
    int r = ty + s * 4;
    sl[r][tx] = proj[((size_t)nm * 256 + t0 + r) * 1024 + cv0 + tx];
  }
  __syncthreads();
#pragma unroll
  for (int s = 0; s < 16; s++) {
    int cvl = ty + s * 4;
    size_t R = (size_t)nm * 960 + cv0 + cvl;
    float v = x[R * 256 + t0 + tx] + bf2f(sl[tx][cvl]);
    ushort h = f2bf(v);
    hi[R * 256 + t0 + tx] = h;
    lo[R * 256 + t0 + tx] = f2bf(v - bf2f(h));
  }
}

extern "C" void kernel_launch(void* const* d_in, const int* in_sizes, int n_in,
                              void* d_out, int out_size, void* d_ws, size_t ws_size,
                              hipStream_t stream) {
  const float* x = (const float*)d_in[0];
  const float* ln_g = (const float*)d_in[1];
  const float* ln_b = (const float*)d_in[2];
  const float* w_qkv = (const float*)d_in[3];
  const float* w_out = (const float*)d_in[4];
  const float* b_out = (const float*)d_in[5];
  const float* w_lin = (const float*)d_in[6];
  const float* b_lin = (const float*)d_in[7];
  float* out = (float*)d_out;

  char* ws = (char*)d_ws;
  size_t off = 0;
  auto alloc = [&](size_t bytes) -> void* {
    void* p = ws + off;
    off = (off + bytes + 255) & ~(size_t)255;
    return p;
  };

  ushort* wqkvT = (ushort*)alloc((size_t)3072 * 960 * 2);
  ushort* woutT = (ushort*)alloc((size_t)1024 * 1024 * 2);
  ushort* whi   = (ushort*)alloc((size_t)65536 * 2);
  ushort* wlo   = (ushort*)alloc((size_t)65536 * 2);
  float*  part  = (float*)alloc((size_t)128 * 4 * 256 * 2 * 4);
  float*  stat  = (float*)alloc((size_t)32768 * 2 * 4);
  ushort* xn    = (ushort*)alloc((size_t)32768 * 960 * 2);
  ushort* qbuf  = (ushort*)alloc((size_t)1024 * 256 * 128 * 2);
  ushort* kbuf  = (ushort*)alloc((size_t)1024 * 256 * 128 * 2);
  ushort* vTbuf = (ushort*)alloc((size_t)1024 * 256 * 128 * 2);
  ushort* attnout = (ushort*)alloc((size_t)32768 * 1024 * 2);
  ushort* proj = qbuf;
  ushort* x2hi = kbuf;
  ushort* x2lo = vTbuf;

  wtrans_kernel<<<dim3(96, 30), 256, 0, stream>>>(w_qkv, wqkvT, 960, 3072);
  wtrans_kernel<<<dim3(32, 32), 256, 0, stream>>>(w_out, woutT, 1024, 960);
  wsplit_kernel<<<dim3(256), 256, 0, stream>>>(w_lin, whi, wlo, 65536);

  ln_part_kernel<<<dim3(4, 128), 256, 0, stream>>>(x, part);
  ln_stat_kernel<<<dim3(128), 256, 0, stream>>>(part, stat);
  ln_apply_kernel<<<dim3(60, 128), 256, 0, stream>>>(x, stat, ln_g, ln_b, xn);

  gemm256<0><<<dim3(12, 128), 512, 0, stream>>>(xn, 960, wqkvT, 960, 30, nullptr, nullptr,
                                                qbuf, kbuf, vTbuf, nullptr, nullptr);
  attn_kernel<<<dim3(4, 1024), 256, 0, stream>>>(qbuf, kbuf, vTbuf, attnout);
  gemm256<1><<<dim3(4, 128), 512, 0, stream>>>(attnout, 1024, woutT, 1024, 32, nullptr, nullptr,
                                               proj, nullptr, nullptr, b_out, nullptr);
  x2split_kernel<<<dim3(60, 128), 256, 0, stream>>>(x, proj, x2hi, x2lo);
  gemm256<2><<<dim3(1, 480), 512, 0, stream>>>(x2hi, 256, whi, 256, 24, x2lo, wlo,
                                               nullptr, nullptr, nullptr, b_lin, out);
}

// Round 4
// 691.406 us; speedup vs baseline: 1.2489x; 1.0043x over previous
//
#include <hip/hip_runtime.h>

typedef unsigned short ushort;
using short8 = __attribute__((ext_vector_type(8))) short;
using f32x4  = __attribute__((ext_vector_type(4))) float;
using i32x4  = __attribute__((ext_vector_type(4))) int;
using us4    = __attribute__((ext_vector_type(4))) ushort;

static __device__ __forceinline__ float bf2f(ushort u) {
  union { unsigned int i; float f; } x; x.i = ((unsigned int)u) << 16; return x.f;
}
static __device__ __forceinline__ ushort f2bf(float f) {
  union { float f; unsigned int i; } x; x.f = f;
  unsigned int u = x.i;
  unsigned int r = u + 0x7fffu + ((u >> 16) & 1u);
  return (ushort)(r >> 16);
}

// async global -> LDS, 16B per lane; LDS dest is wave-uniform base + lane*16
#define GLOAD16(gp, lp)                                                   \
  __builtin_amdgcn_global_load_lds(                                      \
      (const __attribute__((address_space(1))) void*)(gp),               \
      (__attribute__((address_space(3))) void*)(lp), 16, 0, 0)

// ---------------- weight prep ----------------
__global__ __launch_bounds__(256) void wtrans_kernel(const float* __restrict__ in,
                                                     ushort* __restrict__ out,
                                                     int R, int C) {
  __shared__ float sl[32][33];
  int tx = threadIdx.x & 31, ty = threadIdx.x >> 5;
  int c0 = blockIdx.x * 32, r0 = blockIdx.y * 32;
#pragma unroll
  for (int s = 0; s < 4; s++) {
    int r = r0 + ty + s * 8;
    int c = c0 + tx;
    sl[ty + s * 8][tx] = (c < C) ? in[(size_t)r * C + c] : 0.f;
  }
  __syncthreads();
#pragma unroll
  for (int s = 0; s < 4; s++) {
    int c = c0 + ty + s * 8;
    int r = r0 + tx;
    out[(size_t)c * R + r] = f2bf(sl[tx][ty + s * 8]);
  }
}

__global__ void wsplit_kernel(const float* __restrict__ in, ushort* __restrict__ hi,
                              ushort* __restrict__ lo, int n) {
  int i = blockIdx.x * 256 + threadIdx.x;
  if (i < n) {
    float v = in[i];
    ushort h = f2bf(v);
    hi[i] = h;
    lo[i] = f2bf(v - bf2f(h));
  }
}

// ---------------- LayerNorm ----------------
__global__ __launch_bounds__(256) void ln_part_kernel(const float* __restrict__ x,
                                                      float* __restrict__ part) {
  int nm = blockIdx.y, ch = blockIdx.x, t = threadIdx.x;
  float s = 0.f, ss = 0.f;
  const float* base = x + ((size_t)nm * 960 + (size_t)ch * 240) * 256 + t;
#pragma unroll 4
  for (int r = 0; r < 240; r++) {
    float v = base[(size_t)r * 256];
    s += v; ss += v * v;
  }
  float2 o; o.x = s; o.y = ss;
  ((float2*)part)[(nm * 4 + ch) * 256 + t] = o;
}

__global__ __launch_bounds__(256) void ln_stat_kernel(const float* __restrict__ part,
                                                      float* __restrict__ stat) {
  int nm = blockIdx.x, t = threadIdx.x;
  float s = 0.f, ss = 0.f;
#pragma unroll
  for (int ch = 0; ch < 4; ch++) {
    float2 p = ((const float2*)part)[(nm * 4 + ch) * 256 + t];
    s += p.x; ss += p.y;
  }
  float mean = s * (1.f / 960.f);
  float var = ss * (1.f / 960.f) - mean * mean;
  float2 o; o.x = mean; o.y = rsqrtf(var + 1e-5f);
  ((float2*)stat)[nm * 256 + t] = o;
}

__global__ __launch_bounds__(256) void ln_apply_kernel(const float* __restrict__ x,
                                                       const float* __restrict__ stat,
                                                       const float* __restrict__ g,
                                                       const float* __restrict__ b,
                                                       ushort* __restrict__ xn) {
  __shared__ float sl[64][65];
  int nm = blockIdx.y;
  int tb = blockIdx.x & 3, cvb = blockIdx.x >> 2;
  int t0 = tb * 64, cv0 = cvb * 64;
  int tx = threadIdx.x & 63, ty = threadIdx.x >> 6;
#pragma unroll
  for (int s = 0; s < 16; s++) {
    int r = ty + s * 4;
    sl[r][tx] = x[((size_t)nm * 960 + cv0 + r) * 256 + t0 + tx];
  }
  __syncthreads();
  float gg = g[cv0 + tx], bb = b[cv0 + tx];
#pragma unroll
  for (int s = 0; s < 16; s++) {
    int tt = ty + s * 4;
    float2 ms = ((const float2*)stat)[nm * 256 + t0 + tt];
    float v = (sl[tx][tt] - ms.x) * ms.y * gg + bb;
    xn[((size_t)nm * 256 + t0 + tt) * 960 + cv0 + tx] = f2bf(v);
  }
}

// ---------------- 256x256 GEMM, BK=64, 8 waves, 8-phase counted-vmcnt pipeline ----
// LDS 128KB. Regions (16KB each, [256 rows][32 cols]): A(d,kk) @ d*32768+kk*16384,
// B(d,kk) @ 65536 + same. Within region: row stride 64B, 16B-slot s stored at
// s ^ (row&3) (both-sides swizzle: linear gload dest + pre-swizzled source col).
// Per K-tile (64): 4 phases {ds_read subtile | stage 1 half (2 gloads) | bar |
// setprio 16xMFMA | bar}; vmcnt(4) at 2-phase boundaries (vmcnt(0) on last tile).
// MODE 0: QKV epilogue; MODE 1: proj + b_out; MODE 2: 3-seg split-bf16 + tanh.
template <int MODE>
__global__ __launch_bounds__(512, 2) void gemm256(
    const ushort* __restrict__ A, int lda, const ushort* __restrict__ BT, int ldb, int nkt,
    const ushort* __restrict__ Alo, const ushort* __restrict__ Blo,
    ushort* __restrict__ o0, ushort* __restrict__ o1, ushort* __restrict__ o2,
    const float* __restrict__ bias, float* __restrict__ fout) {
  __shared__ char smem[131072];
  int tid = threadIdx.x;
  int l = tid & 63, w = tid >> 6;
  int wr = w >> 2, wc = w & 3;        // wave tile: rows [wr*128,+128), cols [wc*64,+64)
  int lr = l & 15, lg = l >> 4;
  int cb = blockIdx.x * 256, rb = blockIdx.y * 256;

  // staging: granule g = L*512+tid -> row g>>2, phys slot g&3; src slot = (g&3)^(row&3)
  int srow = tid >> 2;
  int scol = ((tid & 3) ^ ((tid >> 2) & 3)) * 8;  // elems within the 32-col half

  // fragment read bases (swizzled): row&3 == lr&3 for all frags
  int swz = (lg ^ (lr & 3)) << 4;
  const char* ArdB = smem + (wr * 128 + lr) * 64 + swz;           // + d*32768 + kk*16384 + i*1024
  const char* BrdB = smem + 65536 + (wc * 64 + lr) * 64 + swz;    // + d*32768 + kk*16384 + j*1024

  auto stage_half = [&](int kt, int kk, int isB) {
    const ushort* P; int ld; int k0;
    if (MODE == 2) {
      int seg = kt >> 2; k0 = (kt & 3) * 64 + kk * 32;
      P = isB ? ((seg == 1) ? Blo : BT) : ((seg == 2) ? Alo : A);
      ld = 256;
    } else {
      P = isB ? BT : A; ld = isB ? ldb : lda; k0 = kt * 64 + kk * 32;
    }
    const ushort* gp = P + (size_t)((isB ? cb : rb) + srow) * ld + k0 + scol;
    char* dst = smem + isB * 65536 + (kt & 1) * 32768 + kk * 16384 + tid * 16;
    GLOAD16(gp, dst);
    GLOAD16(gp + (size_t)128 * ld, dst + 8192);
  };

  f32x4 acc[8][4];
#pragma unroll
  for (int i = 0; i < 8; i++)
#pragma unroll
    for (int j = 0; j < 4; j++) acc[i][j] = (f32x4){0.f, 0.f, 0.f, 0.f};

  // prologue: tile0's 4 halves; wait its k0 halves (retire oldest 4 of 8)
  stage_half(0, 0, 0); stage_half(0, 0, 1); stage_half(0, 1, 0); stage_half(0, 1, 1);
  asm volatile("s_waitcnt vmcnt(4)" ::: "memory");
  __builtin_amdgcn_s_barrier();

  for (int t = 0; t < nkt; t++) {
    const char* Ard = ArdB + (t & 1) * 32768;
    const char* Brd = BrdB + (t & 1) * 32768;
    bool st = (t + 1 < nkt);
    short8 a[4], b[4];

    // ---- phase 1: kk=0, i=0..3 ----
#pragma unroll
    for (int j = 0; j < 4; j++) b[j] = *(const short8*)(Brd + j * 1024);
#pragma unroll
    for (int i = 0; i < 4; i++) a[i] = *(const short8*)(Ard + i * 1024);
    if (st) stage_half(t + 1, 0, 0);
    __builtin_amdgcn_s_barrier();
    __builtin_amdgcn_s_setprio(1);
#pragma unroll
    for (int i = 0; i < 4; i++)
#pragma unroll
      for (int j = 0; j < 4; j++)
        acc[i][j] = __builtin_amdgcn_mfma_f32_16x16x32_bf16(a[i], b[j], acc[i][j], 0, 0, 0);
    __builtin_amdgcn_s_setprio(0);
    __builtin_amdgcn_s_barrier();

    // ---- phase 2: kk=0, i=4..7 ----
#pragma unroll
    for (int i = 0; i < 4; i++) a[i] = *(const short8*)(Ard + (4 + i) * 1024);
    if (st) stage_half(t + 1, 0, 1);
    __builtin_amdgcn_s_barrier();
    __builtin_amdgcn_s_setprio(1);
#pragma unroll
    for (int i = 0; i < 4; i++)
#pragma unroll
      for (int j = 0; j < 4; j++)
        acc[4 + i][j] = __builtin_amdgcn_mfma_f32_16x16x32_bf16(a[i], b[j], acc[4 + i][j], 0, 0, 0);
    __builtin_amdgcn_s_setprio(0);
    if (st) asm volatile("s_waitcnt vmcnt(4)" ::: "memory");   // retire this tile's k1 halves
    else    asm volatile("s_waitcnt vmcnt(0)" ::: "memory");
    __builtin_amdgcn_s_barrier();

    // ---- phase 3: kk=1, i=0..3 ----
#pragma unroll
    for (int j = 0; j < 4; j++) b[j] = *(const short8*)(Brd + 16384 + j * 1024);
#pragma unroll
    for (int i = 0; i < 4; i++) a[i] = *(const short8*)(Ard + 16384 + i * 1024);
    if (st) stage_half(t + 1, 1, 0);
    __builtin_amdgcn_s_barrier();
    __builtin_amdgcn_s_setprio(1);
#pragma unroll
    for (int i = 0; i < 4; i++)
#pragma unroll
      for (int j = 0; j < 4; j++)
        acc[i][j] = __builtin_amdgcn_mfma_f32_16x16x32_bf16(a[i], b[j], acc[i][j], 0, 0, 0);
    __builtin_amdgcn_s_setprio(0);
    __builtin_amdgcn_s_barrier();

    // ---- phase 4: kk=1, i=4..7 ----
#pragma unroll
    for (int i = 0; i < 4; i++) a[i] = *(const short8*)(Ard + 16384 + (4 + i) * 1024);
    if (st) stage_half(t + 1, 1, 1);
    __builtin_amdgcn_s_barrier();
    __builtin_amdgcn_s_setprio(1);
#pragma unroll
    for (int i = 0; i < 4; i++)
#pragma unroll
      for (int j = 0; j < 4; j++)
        acc[4 + i][j] = __builtin_amdgcn_mfma_f32_16x16x32_bf16(a[i], b[j], acc[4 + i][j], 0, 0, 0);
    __builtin_amdgcn_s_setprio(0);
    if (st) asm volatile("s_waitcnt vmcnt(4)" ::: "memory");   // retire next tile's k0 halves
    else    asm volatile("s_waitcnt vmcnt(0)" ::: "memory");
    __builtin_amdgcn_s_barrier();
  }

  int row0 = rb + wr * 128, col0 = cb + wc * 64;
  if (MODE == 0) {
    int nm = rb >> 8;
    int which = cb >> 10;
#pragma unroll
    for (int i = 0; i < 8; i++)
#pragma unroll
      for (int j = 0; j < 4; j++) {
        f32x4 v = acc[i][j];
        int col = col0 + j * 16 + lr;
        int cl = col & 1023;
        int h = cl >> 7, d = cl & 127;
        int nmh = nm * 8 + h;
        int t0 = wr * 128 + i * 16 + lg * 4;
        if (which == 2) {
          us4 pk;
          pk.x = f2bf(v[0]); pk.y = f2bf(v[1]); pk.z = f2bf(v[2]); pk.w = f2bf(v[3]);
          *(us4*)&o2[((size_t)nmh * 128 + d) * 256 + t0] = pk;  // V^T, 8B packed
        } else if (which == 0) {
#pragma unroll
          for (int r = 0; r < 4; r++)
            o0[((size_t)nmh * 256 + t0 + r) * 128 + d] = f2bf(v[r] * 0.08838834764831845f);
        } else {
#pragma unroll
          for (int r = 0; r < 4; r++)
            o1[((size_t)nmh * 256 + t0 + r) * 128 + d] = f2bf(v[r]);
        }
      }
  } else if (MODE == 1) {
#pragma unroll
    for (int i = 0; i < 8; i++)
#pragma unroll
      for (int j = 0; j < 4; j++) {
        f32x4 v = acc[i][j];
        int col = col0 + j * 16 + lr;
        float bb = (col < 960) ? bias[col] : 0.f;
#pragma unroll
        for (int r = 0; r < 4; r++) {
          int row = row0 + i * 16 + lg * 4 + r;
          o0[(size_t)row * 1024 + col] = f2bf(v[r] + bb);
        }
      }
  } else {
#pragma unroll
    for (int i = 0; i < 8; i++)
#pragma unroll
      for (int j = 0; j < 4; j++) {
        f32x4 v = acc[i][j];
        int col = col0 + j * 16 + lr;
        float bb = bias[col];
#pragma unroll
        for (int r = 0; r < 4; r++) {
          int row = row0 + i * 16 + lg * 4 + r;
          fout[(size_t)row * 256 + col] = tanhf(v[r] + bb);
        }
      }
  }
}

// ---------------- fused attention: 64 q-rows per block, full T=256 in regs ----------------
__global__ __launch_bounds__(256) void attn_kernel(const ushort* __restrict__ q,
                                                   const ushort* __restrict__ kb,
                                                   const ushort* __restrict__ vT,
                                                   ushort* __restrict__ ao) {
  __shared__ ushort KVs[128 * 72];
  __shared__ ushort Ps[64 * 264];
  int tid = threadIdx.x;
  int l = tid & 63, w = tid >> 6;
  int lr = l & 15, lg = l >> 4;
  int qb = blockIdx.x;
  int nmh = blockIdx.y;

  short8 aq[4];
  {
    const ushort* qp = q + ((size_t)nmh * 256 + qb * 64 + w * 16 + lr) * 128 + lg * 8;
#pragma unroll
    for (int kk = 0; kk < 4; kk++) aq[kk] = *(const short8*)(qp + kk * 32);
  }

  f32x4 s_acc[16];
#pragma unroll
  for (int f = 0; f < 16; f++) s_acc[f] = (f32x4){0.f, 0.f, 0.f, 0.f};

  for (int ct = 0; ct < 4; ct++) {
    __syncthreads();
#pragma unroll
    for (int u = 0; u < 4; u++) {
      int i = tid + u * 256;
      int r = i >> 4, c = i & 15;
      *(i32x4*)&KVs[r * 136 + c * 8] =
          *(const i32x4*)(kb + ((size_t)nmh * 256 + ct * 64 + r) * 128 + c * 8);
    }
    __syncthreads();
#pragma unroll
    for (int j = 0; j < 4; j++) {
      short8 bk[4];
#pragma unroll
      for (int kk = 0; kk < 4; kk++)
        bk[kk] = *(const short8*)&KVs[(j * 16 + lr) * 136 + kk * 32 + lg * 8];
#pragma unroll
      for (int kk = 0; kk < 4; kk++)
        s_acc[ct * 4 + j] =
            __builtin_amdgcn_mfma_f32_16x16x32_bf16(aq[kk], bk[kk], s_acc[ct * 4 + j], 0, 0, 0);
    }
  }

  float m[4] = {-1e30f, -1e30f, -1e30f, -1e30f};
#pragma unroll
  for (int f = 0; f < 16; f++)
#pragma unroll
    for (int r = 0; r < 4; r++) m[r] = fmaxf(m[r], s_acc[f][r]);
#pragma unroll
  for (int dd = 1; dd < 16; dd <<= 1)
#pragma unroll
    for (int r = 0; r < 4; r++) m[r] = fmaxf(m[r], __shfl_xor(m[r], dd, 64));
  float sum[4] = {0.f, 0.f, 0.f, 0.f};
#pragma unroll
  for (int f = 0; f < 16; f++)
#pragma unroll
    for (int r = 0; r < 4; r++) {
      float p = __expf(s_acc[f][r] - m[r]);
      s_acc[f][r] = p;
      sum[r] += p;
    }
#pragma unroll
  for (int dd = 1; dd < 16; dd <<= 1)
#pragma unroll
    for (int r = 0; r < 4; r++) sum[r] += __shfl_xor(sum[r], dd, 64);
  float rs[4];
#pragma unroll
  for (int r = 0; r < 4; r++) rs[r] = 1.f / sum[r];

#pragma unroll
  for (int f = 0; f < 16; f++)
#pragma unroll
    for (int r = 0; r < 4; r++)
      Ps[(w * 16 + lg * 4 + r) * 264 + f * 16 + lr] = f2bf(s_acc[f][r]);

  f32x4 o_acc[8];
#pragma unroll
  for (int j = 0; j < 8; j++) o_acc[j] = (f32x4){0.f, 0.f, 0.f, 0.f};

  for (int ct = 0; ct < 4; ct++) {
    __syncthreads();
#pragma unroll
    for (int u = 0; u < 4; u++) {
      int i = tid + u * 256;
      int r = i >> 3, c = i & 7;
      *(i32x4*)&KVs[r * 72 + c * 8] =
          *(const i32x4*)(vT + ((size_t)nmh * 128 + r) * 256 + ct * 64 + c * 8);
    }
    __syncthreads();
#pragma unroll
    for (int kk = 0; kk < 2; kk++) {
      short8 ap = *(const short8*)&Ps[(w * 16 + lr) * 264 + ct * 64 + kk * 32 + lg * 8];
#pragma unroll
      for (int j = 0; j < 8; j++) {
        short8 bv = *(const short8*)&KVs[(j * 16 + lr) * 72 + kk * 32 + lg * 8];
        o_acc[j] = __builtin_amdgcn_mfma_f32_16x16x32_bf16(ap, bv, o_acc[j], 0, 0, 0);
      }
    }
  }

  int nm = nmh >> 3, h = nmh & 7;
  int trow0 = qb * 64 + w * 16;
#pragma unroll
  for (int j = 0; j < 8; j++)
#pragma unroll
    for (int r = 0; r < 4; r++) {
      int t = trow0 + lg * 4 + r;
      int d = h * 128 + j * 16 + lr;
      ao[((size_t)nm * 256 + t) * 1024 + d] = f2bf(o_acc[j][r] * rs[r]);
    }
}

// ---------------- residual + reshape + hi/lo split ----------------
__global__ __launch_bounds__(256) void x2split_kernel(const float* __restrict__ x,
                                                      const ushort* __restrict__ proj,
                                                      ushort* __restrict__ hi,
                                                      ushort* __restrict__ lo) {
  __shared__ ushort sl[64][65];
  int nm = blockIdx.y;
  int tb = blockIdx.x & 3, cvb = blockIdx.x >> 2;
  int t0 = tb * 64, cv0 = cvb * 64;
  int tx = threadIdx.x & 63, ty = threadIdx.x >> 6;
#pragma unroll
  for (int s = 0; s < 16; s++) {
    int r = ty + s * 4;
    sl[r][tx] = proj[((size_t)nm * 256 + t0 + r) * 1024 + cv0 + tx];
  }
  __syncthreads();
#pragma unroll
  for (int s = 0; s < 16; s++) {
    int cvl = ty + s * 4;
    size_t R = (size_t)nm * 960 + cv0 + cvl;
    float v = x[R * 256 + t0 + tx] + bf2f(sl[tx][cvl]);
    ushort h = f2bf(v);
    hi[R * 256 + t0 + tx] = h;
    lo[R * 256 + t0 + tx] = f2bf(v - bf2f(h));
  }
}

extern "C" void kernel_launch(void* const* d_in, const int* in_sizes, int n_in,
                              void* d_out, int out_size, void* d_ws, size_t ws_size,
                              hipStream_t stream) {
  const float* x = (const float*)d_in[0];
  const float* ln_g = (const float*)d_in[1];
  const float* ln_b = (const float*)d_in[2];
  const float* w_qkv = (const float*)d_in[3];
  const float* w_out = (const float*)d_in[4];
  const float* b_out = (const float*)d_in[5];
  const float* w_lin = (const float*)d_in[6];
  const float* b_lin = (const float*)d_in[7];
  float* out = (float*)d_out;

  char* ws = (char*)d_ws;
  size_t off = 0;
  auto alloc = [&](size_t bytes) -> void* {
    void* p = ws + off;
    off = (off + bytes + 255) & ~(size_t)255;
    return p;
  };

  ushort* wqkvT = (ushort*)alloc((size_t)3072 * 960 * 2);
  ushort* woutT = (ushort*)alloc((size_t)1024 * 1024 * 2);
  ushort* whi   = (ushort*)alloc((size_t)65536 * 2);
  ushort* wlo   = (ushort*)alloc((size_t)65536 * 2);
  float*  part  = (float*)alloc((size_t)128 * 4 * 256 * 2 * 4);
  float*  stat  = (float*)alloc((size_t)32768 * 2 * 4);
  ushort* xn    = (ushort*)alloc((size_t)32768 * 960 * 2);
  ushort* qbuf  = (ushort*)alloc((size_t)1024 * 256 * 128 * 2);
  ushort* kbuf  = (ushort*)alloc((size_t)1024 * 256 * 128 * 2);
  ushort* vTbuf = (ushort*)alloc((size_t)1024 * 256 * 128 * 2);
  ushort* attnout = (ushort*)alloc((size_t)32768 * 1024 * 2);
  ushort* proj = qbuf;
  ushort* x2hi = kbuf;
  ushort* x2lo = vTbuf;

  wtrans_kernel<<<dim3(96, 30), 256, 0, stream>>>(w_qkv, wqkvT, 960, 3072);
  wtrans_kernel<<<dim3(32, 32), 256, 0, stream>>>(w_out, woutT, 1024, 960);
  wsplit_kernel<<<dim3(256), 256, 0, stream>>>(w_lin, whi, wlo, 65536);

  ln_part_kernel<<<dim3(4, 128), 256, 0, stream>>>(x, part);
  ln_stat_kernel<<<dim3(128), 256, 0, stream>>>(part, stat);
  ln_apply_kernel<<<dim3(60, 128), 256, 0, stream>>>(x, stat, ln_g, ln_b, xn);

  gemm256<0><<<dim3(12, 128), 512, 0, stream>>>(xn, 960, wqkvT, 960, 15, nullptr, nullptr,
                                                qbuf, kbuf, vTbuf, nullptr, nullptr);
  attn_kernel<<<dim3(4, 1024), 256, 0, stream>>>(qbuf, kbuf, vTbuf, attnout);
  gemm256<1><<<dim3(4, 128), 512, 0, stream>>>(attnout, 1024, woutT, 1024, 16, nullptr, nullptr,
                                               proj, nullptr, nullptr, b_out, nullptr);
  x2split_kernel<<<dim3(60, 128), 256, 0, stream>>>(x, proj, x2hi, x2lo);
  gemm256<2><<<dim3(1, 480), 512, 0, stream>>>(x2hi, 256, whi, 256, 12, x2lo, wlo,
                                               nullptr, nullptr, nullptr, b_lin, out);
}

// Round 5
// 683.719 us; speedup vs baseline: 1.2629x; 1.0112x over previous
//
#include <hip/hip_runtime.h>

typedef unsigned short ushort;
using short8 = __attribute__((ext_vector_type(8))) short;
using f32x4  = __attribute__((ext_vector_type(4))) float;
using i32x4  = __attribute__((ext_vector_type(4))) int;
using us4    = __attribute__((ext_vector_type(4))) ushort;

static __device__ __forceinline__ float bf2f(ushort u) {
  union { unsigned int i; float f; } x; x.i = ((unsigned int)u) << 16; return x.f;
}
static __device__ __forceinline__ ushort f2bf(float f) {
  union { float f; unsigned int i; } x; x.f = f;
  unsigned int u = x.i;
  unsigned int r = u + 0x7fffu + ((u >> 16) & 1u);
  return (ushort)(r >> 16);
}

// async global -> LDS, 16B per lane; LDS dest is wave-uniform base + lane*16
#define GLOAD16(gp, lp)                                                   \
  __builtin_amdgcn_global_load_lds(                                      \
      (const __attribute__((address_space(1))) void*)(gp),               \
      (__attribute__((address_space(3))) void*)(lp), 16, 0, 0)

// ---------------- weight prep ----------------
__global__ __launch_bounds__(256) void wtrans_kernel(const float* __restrict__ in,
                                                     ushort* __restrict__ out,
                                                     int R, int C) {
  __shared__ float sl[32][33];
  int tx = threadIdx.x & 31, ty = threadIdx.x >> 5;
  int c0 = blockIdx.x * 32, r0 = blockIdx.y * 32;
#pragma unroll
  for (int s = 0; s < 4; s++) {
    int r = r0 + ty + s * 8;
    int c = c0 + tx;
    sl[ty + s * 8][tx] = (c < C) ? in[(size_t)r * C + c] : 0.f;
  }
  __syncthreads();
#pragma unroll
  for (int s = 0; s < 4; s++) {
    int c = c0 + ty + s * 8;
    int r = r0 + tx;
    out[(size_t)c * R + r] = f2bf(sl[tx][ty + s * 8]);
  }
}

__global__ void wsplit_kernel(const float* __restrict__ in, ushort* __restrict__ hi,
                              ushort* __restrict__ lo, int n) {
  int i = blockIdx.x * 256 + threadIdx.x;
  if (i < n) {
    float v = in[i];
    ushort h = f2bf(v);
    hi[i] = h;
    lo[i] = f2bf(v - bf2f(h));
  }
}

// ---------------- fused LayerNorm: stats + normalize + transpose, x read ONCE ----
// block = (nm, 16-t slab). LDS slab [960][20] f32 (77KB, 2 blocks/CU).
__global__ __launch_bounds__(256) void ln_fused_kernel(const float* __restrict__ x,
                                                       const float* __restrict__ g,
                                                       const float* __restrict__ b,
                                                       ushort* __restrict__ xn) {
  __shared__ float sl[960][20];
  __shared__ float smean[16], srstd[16];
  int tid = threadIdx.x;
  int nm = blockIdx.y;
  int t0 = blockIdx.x * 16;

  // load slab: 960 rows x 16 floats, float4 per thread
  int r0 = tid >> 2, c4 = (tid & 3) * 4;
#pragma unroll
  for (int it = 0; it < 15; it++) {
    int r = it * 64 + r0;
    float4 v = *(const float4*)&x[((size_t)nm * 960 + r) * 256 + t0 + c4];
    *(float4*)&sl[r][c4] = v;
  }
  __syncthreads();

  // stats: group tg (16 threads) handles t = tg
  int tg = tid >> 4, lt = tid & 15;
  float s = 0.f, ss = 0.f;
#pragma unroll 4
  for (int k = 0; k < 60; k++) {
    float v = sl[lt + k * 16][tg];
    s += v; ss += v * v;
  }
#pragma unroll
  for (int d = 1; d < 16; d <<= 1) {
    s += __shfl_xor(s, d, 64);
    ss += __shfl_xor(ss, d, 64);
  }
  if (lt == 0) {
    float mean = s * (1.f / 960.f);
    float var = ss * (1.f / 960.f) - mean * mean;
    smean[tg] = mean;
    srstd[tg] = rsqrtf(var + 1e-5f);
  }
  __syncthreads();

  // normalize + transposed write (coalesced along cv)
  float gg[4], bb[4];
#pragma unroll
  for (int c = 0; c < 4; c++) {
    int col = c * 256 + tid;
    if (col < 960) { gg[c] = g[col]; bb[c] = b[col]; }
  }
#pragma unroll
  for (int t = 0; t < 16; t++) {
    float mean = smean[t], rstd = srstd[t];
#pragma unroll
    for (int c = 0; c < 4; c++) {
      int col = c * 256 + tid;
      if (col < 960)
        xn[((size_t)nm * 256 + t0 + t) * 960 + col] =
            f2bf((sl[col][t] - mean) * rstd * gg[c] + bb[c]);
    }
  }
}

// ---------------- 256x256 GEMM, BK=64, 8 waves, 8-phase counted-vmcnt pipeline ----
// LDS 128KB. Regions (16KB each, [256 rows][32 cols]): A(d,kk) @ d*32768+kk*16384,
// B(d,kk) @ 65536 + same. Within region: row stride 64B, 16B-slot s stored at
// s ^ ((row>>1)&3)  [R3-verified zero-conflict phase: slots mod 8 = {0,4,1,5,2,6,3,7}
// per 8-lane group; the (row&3) variant double-hits and cost 1.77e7 conflicts in R4].
// Both-sides swizzle: linear gload dest + pre-swizzled source col; swizzled reads.
// Per K-tile (64): 4 phases {ds_read subtile | stage 1 half (2 gloads) | bar |
// setprio 16xMFMA | bar}; vmcnt(4) at 2-phase boundaries (vmcnt(0) on last tile).
// MODE 0: QKV epilogue; MODE 1: proj + b_out; MODE 2: 3-seg split-bf16 + tanh.
template <int MODE>
__global__ __launch_bounds__(512, 2) void gemm256(
    const ushort* __restrict__ A, int lda, const ushort* __restrict__ BT, int ldb, int nkt,
    const ushort* __restrict__ Alo, const ushort* __restrict__ Blo,
    ushort* __restrict__ o0, ushort* __restrict__ o1, ushort* __restrict__ o2,
    const float* __restrict__ bias, float* __restrict__ fout) {
  __shared__ char smem[131072];
  int tid = threadIdx.x;
  int l = tid & 63, w = tid >> 6;
  int wr = w >> 2, wc = w & 3;        // wave tile: rows [wr*128,+128), cols [wc*64,+64)
  int lr = l & 15, lg = l >> 4;
  int cb = blockIdx.x * 256, rb = blockIdx.y * 256;

  // staging: granule g = tid -> row g>>2, phys slot g&3; src slot = (g&3)^((row>>1)&3)
  int srow = tid >> 2;
  int scol = ((tid & 3) ^ ((tid >> 3) & 3)) * 8;  // elems within the 32-col half

  // fragment read bases (swizzled): (row>>1)&3 == (lr>>1)&3 for all frags
  int swz = (lg ^ ((lr >> 1) & 3)) << 4;
  const char* ArdB = smem + (wr * 128 + lr) * 64 + swz;           // + d*32768 + kk*16384 + i*1024
  const char* BrdB = smem + 65536 + (wc * 64 + lr) * 64 + swz;    // + d*32768 + kk*16384 + j*1024

  auto stage_half = [&](int kt, int kk, int isB) {
    const ushort* P; int ld; int k0;
    if (MODE == 2) {
      int seg = kt >> 2; k0 = (kt & 3) * 64 + kk * 32;
      P = isB ? ((seg == 1) ? Blo : BT) : ((seg == 2) ? Alo : A);
      ld = 256;
    } else {
      P = isB ? BT : A; ld = isB ? ldb : lda; k0 = kt * 64 + kk * 32;
    }
    const ushort* gp = P + (size_t)((isB ? cb : rb) + srow) * ld + k0 + scol;
    char* dst = smem + isB * 65536 + (kt & 1) * 32768 + kk * 16384 + tid * 16;
    GLOAD16(gp, dst);
    GLOAD16(gp + (size_t)128 * ld, dst + 8192);
  };

  f32x4 acc[8][4];
#pragma unroll
  for (int i = 0; i < 8; i++)
#pragma unroll
    for (int j = 0; j < 4; j++) acc[i][j] = (f32x4){0.f, 0.f, 0.f, 0.f};

  // prologue: tile0's 4 halves; wait its k0 halves (retire oldest 4 of 8)
  stage_half(0, 0, 0); stage_half(0, 0, 1); stage_half(0, 1, 0); stage_half(0, 1, 1);
  asm volatile("s_waitcnt vmcnt(4)" ::: "memory");
  __builtin_amdgcn_s_barrier();

  for (int t = 0; t < nkt; t++) {
    const char* Ard = ArdB + (t & 1) * 32768;
    const char* Brd = BrdB + (t & 1) * 32768;
    bool st = (t + 1 < nkt);
    short8 a[4], b[4];

    // ---- phase 1: kk=0, i=0..3 ----
#pragma unroll
    for (int j = 0; j < 4; j++) b[j] = *(const short8*)(Brd + j * 1024);
#pragma unroll
    for (int i = 0; i < 4; i++) a[i] = *(const short8*)(Ard + i * 1024);
    if (st) stage_half(t + 1, 0, 0);
    __builtin_amdgcn_s_barrier();
    __builtin_amdgcn_s_setprio(1);
#pragma unroll
    for (int i = 0; i < 4; i++)
#pragma unroll
      for (int j = 0; j < 4; j++)
        acc[i][j] = __builtin_amdgcn_mfma_f32_16x16x32_bf16(a[i], b[j], acc[i][j], 0, 0, 0);
    __builtin_amdgcn_s_setprio(0);
    __builtin_amdgcn_s_barrier();

    // ---- phase 2: kk=0, i=4..7 ----
#pragma unroll
    for (int i = 0; i < 4; i++) a[i] = *(const short8*)(Ard + (4 + i) * 1024);
    if (st) stage_half(t + 1, 0, 1);
    __builtin_amdgcn_s_barrier();
    __builtin_amdgcn_s_setprio(1);
#pragma unroll
    for (int i = 0; i < 4; i++)
#pragma unroll
      for (int j = 0; j < 4; j++)
        acc[4 + i][j] = __builtin_amdgcn_mfma_f32_16x16x32_bf16(a[i], b[j], acc[4 + i][j], 0, 0, 0);
    __builtin_amdgcn_s_setprio(0);
    if (st) asm volatile("s_waitcnt vmcnt(4)" ::: "memory");   // retire this tile's k1 halves
    else    asm volatile("s_waitcnt vmcnt(0)" ::: "memory");
    __builtin_amdgcn_s_barrier();

    // ---- phase 3: kk=1, i=0..3 ----
#pragma unroll
    for (int j = 0; j < 4; j++) b[j] = *(const short8*)(Brd + 16384 + j * 1024);
#pragma unroll
    for (int i = 0; i < 4; i++) a[i] = *(const short8*)(Ard + 16384 + i * 1024);
    if (st) stage_half(t + 1, 1, 0);
    __builtin_amdgcn_s_barrier();
    __builtin_amdgcn_s_setprio(1);
#pragma unroll
    for (int i = 0; i < 4; i++)
#pragma unroll
      for (int j = 0; j < 4; j++)
        acc[i][j] = __builtin_amdgcn_mfma_f32_16x16x32_bf16(a[i], b[j], acc[i][j], 0, 0, 0);
    __builtin_amdgcn_s_setprio(0);
    __builtin_amdgcn_s_barrier();

    // ---- phase 4: kk=1, i=4..7 ----
#pragma unroll
    for (int i = 0; i < 4; i++) a[i] = *(const short8*)(Ard + 16384 + (4 + i) * 1024);
    if (st) stage_half(t + 1, 1, 1);
    __builtin_amdgcn_s_barrier();
    __builtin_amdgcn_s_setprio(1);
#pragma unroll
    for (int i = 0; i < 4; i++)
#pragma unroll
      for (int j = 0; j < 4; j++)
        acc[4 + i][j] = __builtin_amdgcn_mfma_f32_16x16x32_bf16(a[i], b[j], acc[4 + i][j], 0, 0, 0);
    __builtin_amdgcn_s_setprio(0);
    if (st) asm volatile("s_waitcnt vmcnt(4)" ::: "memory");   // retire next tile's k0 halves
    else    asm volatile("s_waitcnt vmcnt(0)" ::: "memory");
    __builtin_amdgcn_s_barrier();
  }

  int row0 = rb + wr * 128, col0 = cb + wc * 64;
  if (MODE == 0) {
    int nm = rb >> 8;
    int which = cb >> 10;
#pragma unroll
    for (int i = 0; i < 8; i++)
#pragma unroll
      for (int j = 0; j < 4; j++) {
        f32x4 v = acc[i][j];
        int col = col0 + j * 16 + lr;
        int cl = col & 1023;
        int h = cl >> 7, d = cl & 127;
        int nmh = nm * 8 + h;
        int t0 = wr * 128 + i * 16 + lg * 4;
        if (which == 2) {
          us4 pk;
          pk.x = f2bf(v[0]); pk.y = f2bf(v[1]); pk.z = f2bf(v[2]); pk.w = f2bf(v[3]);
          *(us4*)&o2[((size_t)nmh * 128 + d) * 256 + t0] = pk;  // V^T, 8B packed
        } else if (which == 0) {
#pragma unroll
          for (int r = 0; r < 4; r++)
            o0[((size_t)nmh * 256 + t0 + r) * 128 + d] = f2bf(v[r] * 0.08838834764831845f);
        } else {
#pragma unroll
          for (int r = 0; r < 4; r++)
            o1[((size_t)nmh * 256 + t0 + r) * 128 + d] = f2bf(v[r]);
        }
      }
  } else if (MODE == 1) {
#pragma unroll
    for (int i = 0; i < 8; i++)
#pragma unroll
      for (int j = 0; j < 4; j++) {
        f32x4 v = acc[i][j];
        int col = col0 + j * 16 + lr;
        float bb = (col < 960) ? bias[col] : 0.f;
#pragma unroll
        for (int r = 0; r < 4; r++) {
          int row = row0 + i * 16 + lg * 4 + r;
          o0[(size_t)row * 1024 + col] = f2bf(v[r] + bb);
        }
      }
  } else {
#pragma unroll
    for (int i = 0; i < 8; i++)
#pragma unroll
      for (int j = 0; j < 4; j++) {
        f32x4 v = acc[i][j];
        int col = col0 + j * 16 + lr;
        float bb = bias[col];
#pragma unroll
        for (int r = 0; r < 4; r++) {
          int row = row0 + i * 16 + lg * 4 + r;
          fout[(size_t)row * 256 + col] = tanhf(v[r] + bb);
        }
      }
  }
}

// ---------------- fused attention: 64 q-rows per block, full T=256 in regs ----------------
__global__ __launch_bounds__(256) void attn_kernel(const ushort* __restrict__ q,
                                                   const ushort* __restrict__ kb,
                                                   const ushort* __restrict__ vT,
                                                   ushort* __restrict__ ao) {
  __shared__ ushort KVs[128 * 72];
  __shared__ ushort Ps[64 * 264];
  int tid = threadIdx.x;
  int l = tid & 63, w = tid >> 6;
  int lr = l & 15, lg = l >> 4;
  int qb = blockIdx.x;
  int nmh = blockIdx.y;

  short8 aq[4];
  {
    const ushort* qp = q + ((size_t)nmh * 256 + qb * 64 + w * 16 + lr) * 128 + lg * 8;
#pragma unroll
    for (int kk = 0; kk < 4; kk++) aq[kk] = *(const short8*)(qp + kk * 32);
  }

  f32x4 s_acc[16];
#pragma unroll
  for (int f = 0; f < 16; f++) s_acc[f] = (f32x4){0.f, 0.f, 0.f, 0.f};

  for (int ct = 0; ct < 4; ct++) {
    __syncthreads();
#pragma unroll
    for (int u = 0; u < 4; u++) {
      int i = tid + u * 256;
      int r = i >> 4, c = i & 15;
      *(i32x4*)&KVs[r * 136 + c * 8] =
          *(const i32x4*)(kb + ((size_t)nmh * 256 + ct * 64 + r) * 128 + c * 8);
    }
    __syncthreads();
#pragma unroll
    for (int j = 0; j < 4; j++) {
      short8 bk[4];
#pragma unroll
      for (int kk = 0; kk < 4; kk++)
        bk[kk] = *(const short8*)&KVs[(j * 16 + lr) * 136 + kk * 32 + lg * 8];
#pragma unroll
      for (int kk = 0; kk < 4; kk++)
        s_acc[ct * 4 + j] =
            __builtin_amdgcn_mfma_f32_16x16x32_bf16(aq[kk], bk[kk], s_acc[ct * 4 + j], 0, 0, 0);
    }
  }

  float m[4] = {-1e30f, -1e30f, -1e30f, -1e30f};
#pragma unroll
  for (int f = 0; f < 16; f++)
#pragma unroll
    for (int r = 0; r < 4; r++) m[r] = fmaxf(m[r], s_acc[f][r]);
#pragma unroll
  for (int dd = 1; dd < 16; dd <<= 1)
#pragma unroll
    for (int r = 0; r < 4; r++) m[r] = fmaxf(m[r], __shfl_xor(m[r], dd, 64));
  float sum[4] = {0.f, 0.f, 0.f, 0.f};
#pragma unroll
  for (int f = 0; f < 16; f++)
#pragma unroll
    for (int r = 0; r < 4; r++) {
      float p = __expf(s_acc[f][r] - m[r]);
      s_acc[f][r] = p;
      sum[r] += p;
    }
#pragma unroll
  for (int dd = 1; dd < 16; dd <<= 1)
#pragma unroll
    for (int r = 0; r < 4; r++) sum[r] += __shfl_xor(sum[r], dd, 64);
  float rs[4];
#pragma unroll
  for (int r = 0; r < 4; r++) rs[r] = 1.f / sum[r];

#pragma unroll
  for (int f = 0; f < 16; f++)
#pragma unroll
    for (int r = 0; r < 4; r++)
      Ps[(w * 16 + lg * 4 + r) * 264 + f * 16 + lr] = f2bf(s_acc[f][r]);

  f32x4 o_acc[8];
#pragma unroll
  for (int j = 0; j < 8; j++) o_acc[j] = (f32x4){0.f, 0.f, 0.f, 0.f};

  for (int ct = 0; ct < 4; ct++) {
    __syncthreads();
#pragma unroll
    for (int u = 0; u < 4; u++) {
      int i = tid + u * 256;
      int r = i >> 3, c = i & 7;
      *(i32x4*)&KVs[r * 72 + c * 8] =
          *(const i32x4*)(vT + ((size_t)nmh * 128 + r) * 256 + ct * 64 + c * 8);
    }
    __syncthreads();
#pragma unroll
    for (int kk = 0; kk < 2; kk++) {
      short8 ap = *(const short8*)&Ps[(w * 16 + lr) * 264 + ct * 64 + kk * 32 + lg * 8];
#pragma unroll
      for (int j = 0; j < 8; j++) {
        short8 bv = *(const short8*)&KVs[(j * 16 + lr) * 72 + kk * 32 + lg * 8];
        o_acc[j] = __builtin_amdgcn_mfma_f32_16x16x32_bf16(ap, bv, o_acc[j], 0, 0, 0);
      }
    }
  }

  int nm = nmh >> 3, h = nmh & 7;
  int trow0 = qb * 64 + w * 16;
#pragma unroll
  for (int j = 0; j < 8; j++)
#pragma unroll
    for (int r = 0; r < 4; r++) {
      int t = trow0 + lg * 4 + r;
      int d = h * 128 + j * 16 + lr;
      ao[((size_t)nm * 256 + t) * 1024 + d] = f2bf(o_acc[j][r] * rs[r]);
    }
}

// ---------------- residual + reshape + hi/lo split ----------------
__global__ __launch_bounds__(256) void x2split_kernel(const float* __restrict__ x,
                                                      const ushort* __restrict__ proj,
                                                      ushort* __restrict__ hi,
                                                      ushort* __restrict__ lo) {
  __shared__ ushort sl[64][65];
  int nm = blockIdx.y;
  int tb = blockIdx.x & 3, cvb = blockIdx.x >> 2;
  int t0 = tb * 64, cv0 = cvb * 64;
  int tx = threadIdx.x & 63, ty = threadIdx.x >> 6;
#pragma unroll
  for (int s = 0; s < 16; s++) {
    int r = ty + s * 4;
    sl[r][tx] = proj[((size_t)nm * 256 + t0 + r) * 1024 + cv0 + tx];
  }
  __syncthreads();
#pragma unroll
  for (int s = 0; s < 16; s++) {
    int cvl = ty + s * 4;
    size_t R = (size_t)nm * 960 + cv0 + cvl;
    float v = x[R * 256 + t0 + tx] + bf2f(sl[tx][cvl]);
    ushort h = f2bf(v);
    hi[R * 256 + t0 + tx] = h;
    lo[R * 256 + t0 + tx] = f2bf(v - bf2f(h));
  }
}

extern "C" void kernel_launch(void* const* d_in, const int* in_sizes, int n_in,
                              void* d_out, int out_size, void* d_ws, size_t ws_size,
                              hipStream_t stream) {
  const float* x = (const float*)d_in[0];
  const float* ln_g = (const float*)d_in[1];
  const float* ln_b = (const float*)d_in[2];
  const float* w_qkv = (const float*)d_in[3];
  const float* w_out = (const float*)d_in[4];
  const float* b_out = (const float*)d_in[5];
  const float* w_lin = (const float*)d_in[6];
  const float* b_lin = (const float*)d_in[7];
  float* out = (float*)d_out;

  char* ws = (char*)d_ws;
  size_t off = 0;
  auto alloc = [&](size_t bytes) -> void* {
    void* p = ws + off;
    off = (off + bytes + 255) & ~(size_t)255;
    return p;
  };

  ushort* wqkvT = (ushort*)alloc((size_t)3072 * 960 * 2);
  ushort* woutT = (ushort*)alloc((size_t)1024 * 1024 * 2);
  ushort* whi   = (ushort*)alloc((size_t)65536 * 2);
  ushort* wlo   = (ushort*)alloc((size_t)65536 * 2);
  ushort* xn    = (ushort*)alloc((size_t)32768 * 960 * 2);
  ushort* qbuf  = (ushort*)alloc((size_t)1024 * 256 * 128 * 2);
  ushort* kbuf  = (ushort*)alloc((size_t)1024 * 256 * 128 * 2);
  ushort* vTbuf = (ushort*)alloc((size_t)1024 * 256 * 128 * 2);
  ushort* attnout = (ushort*)alloc((size_t)32768 * 1024 * 2);
  ushort* proj = qbuf;
  ushort* x2hi = kbuf;
  ushort* x2lo = vTbuf;

  wtrans_kernel<<<dim3(96, 30), 256, 0, stream>>>(w_qkv, wqkvT, 960, 3072);
  wtrans_kernel<<<dim3(32, 32), 256, 0, stream>>>(w_out, woutT, 1024, 960);
  wsplit_kernel<<<dim3(256), 256, 0, stream>>>(w_lin, whi, wlo, 65536);

  ln_fused_kernel<<<dim3(16, 128), 256, 0, stream>>>(x, ln_g, ln_b, xn);

  gemm256<0><<<dim3(12, 128), 512, 0, stream>>>(xn, 960, wqkvT, 960, 15, nullptr, nullptr,
                                                qbuf, kbuf, vTbuf, nullptr, nullptr);
  attn_kernel<<<dim3(4, 1024), 256, 0, stream>>>(qbuf, kbuf, vTbuf, attnout);
  gemm256<1><<<dim3(4, 128), 512, 0, stream>>>(attnout, 1024, woutT, 1024, 16, nullptr, nullptr,
                                               proj, nullptr, nullptr, b_out, nullptr);
  x2split_kernel<<<dim3(60, 128), 256, 0, stream>>>(x, proj, x2hi, x2lo);
  gemm256<2><<<dim3(1, 480), 512, 0, stream>>>(x2hi, 256, whi, 256, 12, x2lo, wlo,
                                               nullptr, nullptr, nullptr, b_lin, out);
}

// Round 6
// 623.649 us; speedup vs baseline: 1.3845x; 1.0963x over previous
//
#include <hip/hip_runtime.h>

typedef unsigned short ushort;
using short8 = __attribute__((ext_vector_type(8))) short;
using f32x4  = __attribute__((ext_vector_type(4))) float;
using i32x4  = __attribute__((ext_vector_type(4))) int;
using us4    = __attribute__((ext_vector_type(4))) ushort;

static __device__ __forceinline__ float bf2f(ushort u) {
  union { unsigned int i; float f; } x; x.i = ((unsigned int)u) << 16; return x.f;
}
static __device__ __forceinline__ ushort f2bf(float f) {
  union { float f; unsigned int i; } x; x.f = f;
  unsigned int u = x.i;
  unsigned int r = u + 0x7fffu + ((u >> 16) & 1u);
  return (ushort)(r >> 16);
}

// async global -> LDS, 16B per lane; LDS dest is wave-uniform base + lane*16
#define GLOAD16(gp, lp)                                                   \
  __builtin_amdgcn_global_load_lds(                                      \
      (const __attribute__((address_space(1))) void*)(gp),               \
      (__attribute__((address_space(3))) void*)(lp), 16, 0, 0)

// ---------------- weight prep ----------------
__global__ __launch_bounds__(256) void wtrans_kernel(const float* __restrict__ in,
                                                     ushort* __restrict__ out,
                                                     int R, int C) {
  __shared__ float sl[32][33];
  int tx = threadIdx.x & 31, ty = threadIdx.x >> 5;
  int c0 = blockIdx.x * 32, r0 = blockIdx.y * 32;
#pragma unroll
  for (int s = 0; s < 4; s++) {
    int r = r0 + ty + s * 8;
    int c = c0 + tx;
    sl[ty + s * 8][tx] = (c < C) ? in[(size_t)r * C + c] : 0.f;
  }
  __syncthreads();
#pragma unroll
  for (int s = 0; s < 4; s++) {
    int c = c0 + ty + s * 8;
    int r = r0 + tx;
    out[(size_t)c * R + r] = f2bf(sl[tx][ty + s * 8]);
  }
}

__global__ void wsplit_kernel(const float* __restrict__ in, ushort* __restrict__ hi,
                              ushort* __restrict__ lo, int n) {
  int i = blockIdx.x * 256 + threadIdx.x;
  if (i < n) {
    float v = in[i];
    ushort h = f2bf(v);
    hi[i] = h;
    lo[i] = f2bf(v - bf2f(h));
  }
}

// ---------------- fused LayerNorm: stats + normalize + transpose, x read ONCE ----
__global__ __launch_bounds__(256) void ln_fused_kernel(const float* __restrict__ x,
                                                       const float* __restrict__ g,
                                                       const float* __restrict__ b,
                                                       ushort* __restrict__ xn) {
  __shared__ float sl[960][20];
  __shared__ float smean[16], srstd[16];
  int tid = threadIdx.x;
  int nm = blockIdx.y;
  int t0 = blockIdx.x * 16;

  int r0 = tid >> 2, c4 = (tid & 3) * 4;
#pragma unroll
  for (int it = 0; it < 15; it++) {
    int r = it * 64 + r0;
    float4 v = *(const float4*)&x[((size_t)nm * 960 + r) * 256 + t0 + c4];
    *(float4*)&sl[r][c4] = v;
  }
  __syncthreads();

  int tg = tid >> 4, lt = tid & 15;
  float s = 0.f, ss = 0.f;
#pragma unroll 4
  for (int k = 0; k < 60; k++) {
    float v = sl[lt + k * 16][tg];
    s += v; ss += v * v;
  }
#pragma unroll
  for (int d = 1; d < 16; d <<= 1) {
    s += __shfl_xor(s, d, 64);
    ss += __shfl_xor(ss, d, 64);
  }
  if (lt == 0) {
    float mean = s * (1.f / 960.f);
    float var = ss * (1.f / 960.f) - mean * mean;
    smean[tg] = mean;
    srstd[tg] = rsqrtf(var + 1e-5f);
  }
  __syncthreads();

  float gg[4], bb[4];
#pragma unroll
  for (int c = 0; c < 4; c++) {
    int col = c * 256 + tid;
    if (col < 960) { gg[c] = g[col]; bb[c] = b[col]; }
  }
#pragma unroll
  for (int t = 0; t < 16; t++) {
    float mean = smean[t], rstd = srstd[t];
#pragma unroll
    for (int c = 0; c < 4; c++) {
      int col = c * 256 + tid;
      if (col < 960)
        xn[((size_t)nm * 256 + t0 + t) * 960 + col] =
            f2bf((sl[col][t] - mean) * rstd * gg[c] + bb[c]);
    }
  }
}

// ---------------- 256x256 GEMM, BK=64, 8 waves, 8-phase counted-vmcnt pipeline ----
// (structure as R5; zero bank conflicts verified)
// MODE 0: QKV epilogue; MODE 1: proj^T packed + b_out; MODE 2: 3-seg split-bf16 + tanh.
template <int MODE>
__global__ __launch_bounds__(512, 2) void gemm256(
    const ushort* __restrict__ A, int lda, const ushort* __restrict__ BT, int ldb, int nkt,
    const ushort* __restrict__ Alo, const ushort* __restrict__ Blo,
    ushort* __restrict__ o0, ushort* __restrict__ o1, ushort* __restrict__ o2,
    const float* __restrict__ bias, float* __restrict__ fout) {
  __shared__ char smem[131072];
  int tid = threadIdx.x;
  int l = tid & 63, w = tid >> 6;
  int wr = w >> 2, wc = w & 3;
  int lr = l & 15, lg = l >> 4;
  int cb = blockIdx.x * 256, rb = blockIdx.y * 256;

  int srow = tid >> 2;
  int scol = ((tid & 3) ^ ((tid >> 3) & 3)) * 8;

  int swz = (lg ^ ((lr >> 1) & 3)) << 4;
  const char* ArdB = smem + (wr * 128 + lr) * 64 + swz;
  const char* BrdB = smem + 65536 + (wc * 64 + lr) * 64 + swz;

  auto stage_half = [&](int kt, int kk, int isB) {
    const ushort* P; int ld; int k0;
    if (MODE == 2) {
      int seg = kt >> 2; k0 = (kt & 3) * 64 + kk * 32;
      P = isB ? ((seg == 1) ? Blo : BT) : ((seg == 2) ? Alo : A);
      ld = 256;
    } else {
      P = isB ? BT : A; ld = isB ? ldb : lda; k0 = kt * 64 + kk * 32;
    }
    const ushort* gp = P + (size_t)((isB ? cb : rb) + srow) * ld + k0 + scol;
    char* dst = smem + isB * 65536 + (kt & 1) * 32768 + kk * 16384 + tid * 16;
    GLOAD16(gp, dst);
    GLOAD16(gp + (size_t)128 * ld, dst + 8192);
  };

  f32x4 acc[8][4];
#pragma unroll
  for (int i = 0; i < 8; i++)
#pragma unroll
    for (int j = 0; j < 4; j++) acc[i][j] = (f32x4){0.f, 0.f, 0.f, 0.f};

  stage_half(0, 0, 0); stage_half(0, 0, 1); stage_half(0, 1, 0); stage_half(0, 1, 1);
  asm volatile("s_waitcnt vmcnt(4)" ::: "memory");
  __builtin_amdgcn_s_barrier();

  for (int t = 0; t < nkt; t++) {
    const char* Ard = ArdB + (t & 1) * 32768;
    const char* Brd = BrdB + (t & 1) * 32768;
    bool st = (t + 1 < nkt);
    short8 a[4], b[4];

#pragma unroll
    for (int j = 0; j < 4; j++) b[j] = *(const short8*)(Brd + j * 1024);
#pragma unroll
    for (int i = 0; i < 4; i++) a[i] = *(const short8*)(Ard + i * 1024);
    if (st) stage_half(t + 1, 0, 0);
    __builtin_amdgcn_s_barrier();
    __builtin_amdgcn_s_setprio(1);
#pragma unroll
    for (int i = 0; i < 4; i++)
#pragma unroll
      for (int j = 0; j < 4; j++)
        acc[i][j] = __builtin_amdgcn_mfma_f32_16x16x32_bf16(a[i], b[j], acc[i][j], 0, 0, 0);
    __builtin_amdgcn_s_setprio(0);
    __builtin_amdgcn_s_barrier();

#pragma unroll
    for (int i = 0; i < 4; i++) a[i] = *(const short8*)(Ard + (4 + i) * 1024);
    if (st) stage_half(t + 1, 0, 1);
    __builtin_amdgcn_s_barrier();
    __builtin_amdgcn_s_setprio(1);
#pragma unroll
    for (int i = 0; i < 4; i++)
#pragma unroll
      for (int j = 0; j < 4; j++)
        acc[4 + i][j] = __builtin_amdgcn_mfma_f32_16x16x32_bf16(a[i], b[j], acc[4 + i][j], 0, 0, 0);
    __builtin_amdgcn_s_setprio(0);
    if (st) asm volatile("s_waitcnt vmcnt(4)" ::: "memory");
    else    asm volatile("s_waitcnt vmcnt(0)" ::: "memory");
    __builtin_amdgcn_s_barrier();

#pragma unroll
    for (int j = 0; j < 4; j++) b[j] = *(const short8*)(Brd + 16384 + j * 1024);
#pragma unroll
    for (int i = 0; i < 4; i++) a[i] = *(const short8*)(Ard + 16384 + i * 1024);
    if (st) stage_half(t + 1, 1, 0);
    __builtin_amdgcn_s_barrier();
    __builtin_amdgcn_s_setprio(1);
#pragma unroll
    for (int i = 0; i < 4; i++)
#pragma unroll
      for (int j = 0; j < 4; j++)
        acc[i][j] = __builtin_amdgcn_mfma_f32_16x16x32_bf16(a[i], b[j], acc[i][j], 0, 0, 0);
    __builtin_amdgcn_s_setprio(0);
    __builtin_amdgcn_s_barrier();

#pragma unroll
    for (int i = 0; i < 4; i++) a[i] = *(const short8*)(Ard + 16384 + (4 + i) * 1024);
    if (st) stage_half(t + 1, 1, 1);
    __builtin_amdgcn_s_barrier();
    __builtin_amdgcn_s_setprio(1);
#pragma unroll
    for (int i = 0; i < 4; i++)
#pragma unroll
      for (int j = 0; j < 4; j++)
        acc[4 + i][j] = __builtin_amdgcn_mfma_f32_16x16x32_bf16(a[i], b[j], acc[4 + i][j], 0, 0, 0);
    __builtin_amdgcn_s_setprio(0);
    if (st) asm volatile("s_waitcnt vmcnt(4)" ::: "memory");
    else    asm volatile("s_waitcnt vmcnt(0)" ::: "memory");
    __builtin_amdgcn_s_barrier();
  }

  int row0 = rb + wr * 128, col0 = cb + wc * 64;
  if (MODE == 0) {
    int nm = rb >> 8;
    int which = cb >> 10;
#pragma unroll
    for (int i = 0; i < 8; i++)
#pragma unroll
      for (int j = 0; j < 4; j++) {
        f32x4 v = acc[i][j];
        int col = col0 + j * 16 + lr;
        int cl = col & 1023;
        int h = cl >> 7, d = cl & 127;
        int nmh = nm * 8 + h;
        int t0 = wr * 128 + i * 16 + lg * 4;
        if (which == 2) {
          us4 pk;
          pk.x = f2bf(v[0]); pk.y = f2bf(v[1]); pk.z = f2bf(v[2]); pk.w = f2bf(v[3]);
          *(us4*)&o2[((size_t)nmh * 128 + d) * 256 + t0] = pk;  // V^T, 8B packed
        } else if (which == 0) {
#pragma unroll
          for (int r = 0; r < 4; r++)
            o0[((size_t)nmh * 256 + t0 + r) * 128 + d] = f2bf(v[r] * 0.08838834764831845f);
        } else {
#pragma unroll
          for (int r = 0; r < 4; r++)
            o1[((size_t)nmh * 256 + t0 + r) * 128 + d] = f2bf(v[r]);
        }
      }
  } else if (MODE == 1) {
    // proj^T: [nm][cv(1024-padded)][t], packed us4 along t (like V^T)
    int nm = rb >> 8;
#pragma unroll
    for (int i = 0; i < 8; i++)
#pragma unroll
      for (int j = 0; j < 4; j++) {
        f32x4 v = acc[i][j];
        int col = col0 + j * 16 + lr;
        float bb = (col < 960) ? bias[col] : 0.f;
        int t0 = wr * 128 + i * 16 + lg * 4;
        us4 pk;
        pk.x = f2bf(v[0] + bb); pk.y = f2bf(v[1] + bb);
        pk.z = f2bf(v[2] + bb); pk.w = f2bf(v[3] + bb);
        *(us4*)&o0[((size_t)nm * 1024 + col) * 256 + t0] = pk;
      }
  } else {
#pragma unroll
    for (int i = 0; i < 8; i++)
#pragma unroll
      for (int j = 0; j < 4; j++) {
        f32x4 v = acc[i][j];
        int col = col0 + j * 16 + lr;
        float bb = bias[col];
#pragma unroll
        for (int r = 0; r < 4; r++) {
          int row = row0 + i * 16 + lg * 4 + r;
          fout[(size_t)row * 256 + col] = tanhf(v[r] + bb);
        }
      }
  }
}

// ---------------- attention v2: one block per head, K/V staged once ----------------
// 512 thr / 8 waves; wave w owns q-rows [w*32, w*32+32).
// LDS: K[256][128] @0 (64KB, swz slot^=(row&7)); V^T[128][256] @65536 (64KB, same swz).
// After QK^T + one barrier, per-wave P chunks [32][72] overwrite K region (private).
__global__ __launch_bounds__(512, 2) void attn2_kernel(const ushort* __restrict__ q,
                                                       const ushort* __restrict__ kb,
                                                       const ushort* __restrict__ vT,
                                                       ushort* __restrict__ ao) {
  __shared__ char smem[131072];
  int tid = threadIdx.x;
  int l = tid & 63, w = tid >> 6;
  int lr = l & 15, lg = l >> 4;
  int nmh = blockIdx.x;

  const ushort* kbase = kb + (size_t)nmh * 32768;
  const ushort* vbase = vT + (size_t)nmh * 32768;

  // stage K (8 x gload16): granule g = u*512 + w*64 + l
#pragma unroll
  for (int u = 0; u < 8; u++) {
    int row = u * 32 + w * 4 + (l >> 4);
    int slot = l & 15;
    GLOAD16(kbase + row * 128 + ((slot ^ (row & 7)) * 8), smem + u * 8192 + w * 1024);
  }
  // q fragments (8 x 16B global loads)
  short8 aq[2][4];
  {
    const ushort* qp = q + (size_t)nmh * 32768 + (size_t)(w * 32 + lr) * 128 + lg * 8;
#pragma unroll
    for (int i = 0; i < 2; i++)
#pragma unroll
      for (int kk = 0; kk < 4; kk++) aq[i][kk] = *(const short8*)(qp + i * 2048 + kk * 32);
  }
  // stage V^T (8 x gload16)
#pragma unroll
  for (int u = 0; u < 8; u++) {
    int row = u * 16 + w * 2 + (l >> 5);
    int slot = l & 31;
    GLOAD16(vbase + row * 256 + ((slot ^ (row & 7)) * 8),
            smem + 65536 + u * 8192 + w * 1024);
  }
  asm volatile("s_waitcnt vmcnt(8)" ::: "memory");  // K + q done; V in flight
  __builtin_amdgcn_s_barrier();

  // QK^T: s_acc[i][j] = q-rows (i*16) x kv-cols (j*16), K from LDS
  f32x4 s_acc[2][16];
#pragma unroll
  for (int i = 0; i < 2; i++)
#pragma unroll
    for (int j = 0; j < 16; j++) s_acc[i][j] = (f32x4){0.f, 0.f, 0.f, 0.f};
#pragma unroll
  for (int j = 0; j < 16; j++) {
    short8 bk[4];
#pragma unroll
    for (int kk = 0; kk < 4; kk++)
      bk[kk] = *(const short8*)(smem + (j * 16 + lr) * 256 + (((kk * 4 + lg) ^ (lr & 7)) << 4));
#pragma unroll
    for (int i = 0; i < 2; i++)
#pragma unroll
      for (int kk = 0; kk < 4; kk++)
        s_acc[i][j] = __builtin_amdgcn_mfma_f32_16x16x32_bf16(aq[i][kk], bk[kk], s_acc[i][j], 0, 0, 0);
  }

  // softmax per row (rows: i, lg*4+r; cols: j, lr)
  float m[2][4], sum[2][4], rs[2][4];
#pragma unroll
  for (int i = 0; i < 2; i++)
#pragma unroll
    for (int r = 0; r < 4; r++) m[i][r] = -1e30f;
#pragma unroll
  for (int i = 0; i < 2; i++)
#pragma unroll
    for (int j = 0; j < 16; j++)
#pragma unroll
      for (int r = 0; r < 4; r++) m[i][r] = fmaxf(m[i][r], s_acc[i][j][r]);
#pragma unroll
  for (int d = 1; d < 16; d <<= 1)
#pragma unroll
    for (int i = 0; i < 2; i++)
#pragma unroll
      for (int r = 0; r < 4; r++) m[i][r] = fmaxf(m[i][r], __shfl_xor(m[i][r], d, 64));
#pragma unroll
  for (int i = 0; i < 2; i++)
#pragma unroll
    for (int r = 0; r < 4; r++) sum[i][r] = 0.f;
#pragma unroll
  for (int i = 0; i < 2; i++)
#pragma unroll
    for (int j = 0; j < 16; j++)
#pragma unroll
      for (int r = 0; r < 4; r++) {
        float p = __expf(s_acc[i][j][r] - m[i][r]);
        s_acc[i][j][r] = p;
        sum[i][r] += p;
      }
#pragma unroll
  for (int d = 1; d < 16; d <<= 1)
#pragma unroll
    for (int i = 0; i < 2; i++)
#pragma unroll
      for (int r = 0; r < 4; r++) sum[i][r] += __shfl_xor(sum[i][r], d, 64);
#pragma unroll
  for (int i = 0; i < 2; i++)
#pragma unroll
    for (int r = 0; r < 4; r++) rs[i][r] = 1.f / sum[i][r];

  __builtin_amdgcn_s_barrier();                      // all waves done reading K region
  asm volatile("s_waitcnt vmcnt(0)" ::: "memory");   // V^T resident

  // PV in 4 kv-chunks of 64; P chunk via private LDS [32][72]
  char* Pb = smem + w * 4608;
  f32x4 o_acc[2][8];
#pragma unroll
  for (int i = 0; i < 2; i++)
#pragma unroll
    for (int j = 0; j < 8; j++) o_acc[i][j] = (f32x4){0.f, 0.f, 0.f, 0.f};

#pragma unroll
  for (int ct = 0; ct < 4; ct++) {
#pragma unroll
    for (int i = 0; i < 2; i++)
#pragma unroll
      for (int jj = 0; jj < 4; jj++)
#pragma unroll
        for (int r = 0; r < 4; r++)
          *(ushort*)(Pb + (i * 16 + lg * 4 + r) * 144 + (jj * 16 + lr) * 2) =
              f2bf(s_acc[i][ct * 4 + jj][r]);
    short8 pa[2][2];
#pragma unroll
    for (int i = 0; i < 2; i++)
#pragma unroll
      for (int kk = 0; kk < 2; kk++)
        pa[i][kk] = *(const short8*)(Pb + (i * 16 + lr) * 144 + kk * 64 + lg * 16);
#pragma unroll
    for (int j = 0; j < 8; j++) {
      short8 bv[2];
#pragma unroll
      for (int kk = 0; kk < 2; kk++)
        bv[kk] = *(const short8*)(smem + 65536 + (j * 16 + lr) * 512 +
                                  (((ct * 8 + kk * 4 + lg) ^ (lr & 7)) << 4));
#pragma unroll
      for (int i = 0; i < 2; i++)
#pragma unroll
        for (int kk = 0; kk < 2; kk++)
          o_acc[i][j] = __builtin_amdgcn_mfma_f32_16x16x32_bf16(pa[i][kk], bv[kk], o_acc[i][j], 0, 0, 0);
    }
  }

  int nm = nmh >> 3, h = nmh & 7;
#pragma unroll
  for (int i = 0; i < 2; i++)
#pragma unroll
    for (int j = 0; j < 8; j++)
#pragma unroll
      for (int r = 0; r < 4; r++) {
        int t = w * 32 + i * 16 + lg * 4 + r;
        int d = h * 128 + j * 16 + lr;
        ao[((size_t)nm * 256 + t) * 1024 + d] = f2bf(o_acc[i][j][r] * rs[i][r]);
      }
}

// ---------------- residual + split, pure elementwise (proj^T matches x layout) ----
__global__ __launch_bounds__(256) void x2split_kernel(const float* __restrict__ x,
                                                      const ushort* __restrict__ projT,
                                                      ushort* __restrict__ hi,
                                                      ushort* __restrict__ lo) {
  int nm = blockIdx.y;
  int cv = blockIdx.x * 4 + (threadIdx.x >> 6);
  int t = (threadIdx.x & 63) * 4;
  size_t xi = ((size_t)nm * 960 + cv) * 256 + t;
  f32x4 xv = *(const f32x4*)&x[xi];
  us4 pv = *(const us4*)&projT[((size_t)nm * 1024 + cv) * 256 + t];
  us4 h, lo4;
#pragma unroll
  for (int e = 0; e < 4; e++) {
    float s = xv[e] + bf2f(pv[e]);
    ushort hh = f2bf(s);
    h[e] = hh;
    lo4[e] = f2bf(s - bf2f(hh));
  }
  *(us4*)&hi[xi] = h;
  *(us4*)&lo[xi] = lo4;
}

extern "C" void kernel_launch(void* const* d_in, const int* in_sizes, int n_in,
                              void* d_out, int out_size, void* d_ws, size_t ws_size,
                              hipStream_t stream) {
  const float* x = (const float*)d_in[0];
  const float* ln_g = (const float*)d_in[1];
  const float* ln_b = (const float*)d_in[2];
  const float* w_qkv = (const float*)d_in[3];
  const float* w_out = (const float*)d_in[4];
  const float* b_out = (const float*)d_in[5];
  const float* w_lin = (const float*)d_in[6];
  const float* b_lin = (const float*)d_in[7];
  float* out = (float*)d_out;

  char* ws = (char*)d_ws;
  size_t off = 0;
  auto alloc = [&](size_t bytes) -> void* {
    void* p = ws + off;
    off = (off + bytes + 255) & ~(size_t)255;
    return p;
  };

  ushort* wqkvT = (ushort*)alloc((size_t)3072 * 960 * 2);
  ushort* woutT = (ushort*)alloc((size_t)1024 * 1024 * 2);
  ushort* whi   = (ushort*)alloc((size_t)65536 * 2);
  ushort* wlo   = (ushort*)alloc((size_t)65536 * 2);
  ushort* xn    = (ushort*)alloc((size_t)32768 * 960 * 2);
  ushort* qbuf  = (ushort*)alloc((size_t)1024 * 256 * 128 * 2);
  ushort* kbuf  = (ushort*)alloc((size_t)1024 * 256 * 128 * 2);
  ushort* vTbuf = (ushort*)alloc((size_t)1024 * 256 * 128 * 2);
  ushort* attnout = (ushort*)alloc((size_t)32768 * 1024 * 2);
  ushort* projT = qbuf;   // [nm][1024][256] packed-t, 67MB == qbuf size
  ushort* x2hi  = kbuf;
  ushort* x2lo  = vTbuf;

  wtrans_kernel<<<dim3(96, 30), 256, 0, stream>>>(w_qkv, wqkvT, 960, 3072);
  wtrans_kernel<<<dim3(32, 32), 256, 0, stream>>>(w_out, woutT, 1024, 960);
  wsplit_kernel<<<dim3(256), 256, 0, stream>>>(w_lin, whi, wlo, 65536);

  ln_fused_kernel<<<dim3(16, 128), 256, 0, stream>>>(x, ln_g, ln_b, xn);

  gemm256<0><<<dim3(12, 128), 512, 0, stream>>>(xn, 960, wqkvT, 960, 15, nullptr, nullptr,
                                                qbuf, kbuf, vTbuf, nullptr, nullptr);
  attn2_kernel<<<dim3(1024), 512, 0, stream>>>(qbuf, kbuf, vTbuf, attnout);
  gemm256<1><<<dim3(4, 128), 512, 0, stream>>>(attnout, 1024, woutT, 1024, 16, nullptr, nullptr,
                                               projT, nullptr, nullptr, b_out, nullptr);
  x2split_kernel<<<dim3(240, 128), 256, 0, stream>>>(x, projT, x2hi, x2lo);
  gemm256<2><<<dim3(1, 480), 512, 0, stream>>>(x2hi, 256, whi, 256, 12, x2lo, wlo,
                                               nullptr, nullptr, nullptr, b_lin, out);
}